// Round 1
// baseline (203.544 us; speedup 1.0000x reference)
//
#include <hip/hip_runtime.h>
#include <math.h>

#define BB 4
#define SS 2048
#define DD 512
#define HH 8
#define HD 64
#define NTOK (BB*SS)
#define EPS 1e-5f
#define NE ((size_t)NTOK * DD)
#define WN ((size_t)DD * DD)
#define LOG2E 1.4426950408889634f

typedef _Float16 half8v __attribute__((ext_vector_type(8)));
typedef _Float16 half4v __attribute__((ext_vector_type(4)));
typedef _Float16 half2v __attribute__((ext_vector_type(2)));
typedef float f32x4 __attribute__((ext_vector_type(4)));

__device__ __forceinline__ float fast_exp2(float x) {
#if __has_builtin(__builtin_amdgcn_exp2f)
    return __builtin_amdgcn_exp2f(x);
#else
    return __expf(x * 0.6931471805599453f);
#endif
}

__device__ __forceinline__ half2v pack2(float a, float b) {
    return __builtin_bit_cast(half2v, __builtin_amdgcn_cvt_pkrtz(a, b));
}

__device__ __forceinline__ half4v pack4(float a, float b, float c, float d) {
    half2v lo = pack2(a, b);
    half2v hi = pack2(c, d);
    half4v r; r[0] = lo[0]; r[1] = lo[1]; r[2] = hi[0]; r[3] = hi[1];
    return r;
}

__device__ __forceinline__ void gload_lds16(const void* g, void* l) {
    __builtin_amdgcn_global_load_lds(
        (const __attribute__((address_space(1))) unsigned int*)g,
        (__attribute__((address_space(3))) unsigned int*)l, 16, 0, 0);
}

// ---------------- final LayerNorm (with residual) ----------------
__global__ __launch_bounds__(256) void ln_kernel(const float* __restrict__ x,
                                                 const float* __restrict__ res,
                                                 const float* __restrict__ gamma,
                                                 const float* __restrict__ beta,
                                                 float* __restrict__ y) {
    int row = blockIdx.x;
    const float* xr = x + (size_t)row * DD;
    int t = threadIdx.x;
    float2 v = ((const float2*)xr)[t];
    {
        float2 r = ((const float2*)(res + (size_t)row * DD))[t];
        v.x += r.x; v.y += r.y;
    }
    float s = v.x + v.y;
    float ss = v.x * v.x + v.y * v.y;
    #pragma unroll
    for (int off = 32; off; off >>= 1) {
        s  += __shfl_down(s,  off);
        ss += __shfl_down(ss, off);
    }
    __shared__ float ws0[4], ws1[4];
    int wid = t >> 6, lane = t & 63;
    if (lane == 0) { ws0[wid] = s; ws1[wid] = ss; }
    __syncthreads();
    __shared__ float mu_s, rstd_s;
    if (t == 0) {
        float S0 = ws0[0] + ws0[1] + ws0[2] + ws0[3];
        float S1 = ws1[0] + ws1[1] + ws1[2] + ws1[3];
        float mu = S0 * (1.0f / DD);
        float var = S1 * (1.0f / DD) - mu * mu;
        mu_s = mu;
        rstd_s = rsqrtf(var + EPS);
    }
    __syncthreads();
    float mu = mu_s, rstd = rstd_s;
    float2 g = ((const float2*)gamma)[t];
    float2 bb = ((const float2*)beta)[t];
    float2 o;
    o.x = (v.x - mu) * rstd * g.x + bb.x;
    o.y = (v.y - mu) * rstd * g.y + bb.y;
    ((float2*)(y + (size_t)row * DD))[t] = o;
}

// ---------------- prep: LN(seq_v) + cast q/k + cast W (fused) --------------
__global__ __launch_bounds__(256) void prep_kernel(const float* __restrict__ seq_v,
                                                   const float* __restrict__ seq_q,
                                                   const float* __restrict__ seq_k,
                                                   const float* __restrict__ W1,
                                                   const float* __restrict__ W2,
                                                   const float* __restrict__ W3,
                                                   const float* __restrict__ gamma,
                                                   const float* __restrict__ beta,
                                                   float* __restrict__ v_in,
                                                   _Float16* __restrict__ v16,
                                                   _Float16* __restrict__ qk16,
                                                   _Float16* __restrict__ w16) {
    int bid = blockIdx.x;
    int t = threadIdx.x;
    if (bid < NTOK) {
        int row = bid;
        float2 v = ((const float2*)(seq_v + (size_t)row * DD))[t];
        float s = v.x + v.y;
        float ss = v.x * v.x + v.y * v.y;
        #pragma unroll
        for (int off = 32; off; off >>= 1) {
            s  += __shfl_down(s,  off);
            ss += __shfl_down(ss, off);
        }
        __shared__ float ws0[4], ws1[4];
        int wid = t >> 6, lane = t & 63;
        if (lane == 0) { ws0[wid] = s; ws1[wid] = ss; }
        __syncthreads();
        __shared__ float mu_s, rstd_s;
        if (t == 0) {
            float S0 = ws0[0] + ws0[1] + ws0[2] + ws0[3];
            float S1 = ws1[0] + ws1[1] + ws1[2] + ws1[3];
            float mu = S0 * (1.0f / DD);
            float var = S1 * (1.0f / DD) - mu * mu;
            mu_s = mu;
            rstd_s = rsqrtf(var + EPS);
        }
        __syncthreads();
        float mu = mu_s, rstd = rstd_s;
        float2 g = ((const float2*)gamma)[t];
        float2 bb = ((const float2*)beta)[t];
        float2 o;
        o.x = (v.x - mu) * rstd * g.x + bb.x;
        o.y = (v.y - mu) * rstd * g.y + bb.y;
        ((float2*)(v_in + (size_t)row * DD))[t] = o;
        *(half2v*)&v16[(size_t)row * DD + 2 * t] = pack2(o.x, o.y);
    } else if (bid < 2 * NTOK) {
        size_t i = ((size_t)(bid - NTOK) * 256 + t) * 4;
        const float* src = (i < NE) ? (seq_q + i) : (seq_k + (i - NE));
        float4 v = *(const float4*)src;
        *(half4v*)(qk16 + i) = pack4(v.x, v.y, v.z, v.w);
    } else {
        size_t i = ((size_t)(bid - 2 * NTOK) * 256 + t) * 4;
        const float* src; float sc;
        if (i < WN)          { src = W1 + i;            sc = LOG2E; }
        else if (i < 2 * WN) { src = W2 + (i - WN);     sc = 1.0f; }
        else                 { src = W3 + (i - 2 * WN); sc = 1.0f; }
        float4 v = *(const float4*)src;
        *(half4v*)(w16 + i) = pack4(v.x * sc, v.y * sc, v.z * sc, v.w * sc);
    }
}

// ---------------- MFMA GEMM: all three projections in one launch ------------
#define GBM 128
#define GBN 128
#define GBK 64
__global__ __launch_bounds__(256) void gemm_mfma(const _Float16* __restrict__ Aall,
                                                 const _Float16* __restrict__ Wall,
                                                 _Float16* __restrict__ Call,
                                                 _Float16* __restrict__ vtOut) {
    __shared__ __align__(16) _Float16 As[GBM * GBK];
    __shared__ __align__(16) _Float16 Ws[GBN * GBK];
    int z = blockIdx.z;
    bool isv = (z == 2);
    const _Float16* A = Aall + (size_t)z * NE;
    const _Float16* W = Wall + (size_t)z * WN;
    int t = threadIdx.x, w = t >> 6, lane = t & 63, q = lane >> 4, ln = lane & 15;
    int lrow = lane >> 3, lseg = lane & 7;
    int m0 = blockIdx.y * GBM, n0 = blockIdx.x * GBN;
    int wm = w & 1, wn = w >> 1;
    f32x4 acc[4][4];
    #pragma unroll
    for (int mt = 0; mt < 4; ++mt)
        #pragma unroll
        for (int nt = 0; nt < 4; ++nt)
            acc[mt][nt] = (f32x4){0.f, 0.f, 0.f, 0.f};

    int gs = lseg ^ lrow;
    for (int k0 = 0; k0 < DD; k0 += GBK) {
        #pragma unroll
        for (int p = 0; p < 4; ++p) {
            int r = w * 32 + p * 8 + lrow;
            gload_lds16(A + (size_t)(m0 + r) * DD + k0 + gs * 8,
                        As + (size_t)(w * 32 + p * 8) * GBK);
            gload_lds16(W + (size_t)(n0 + r) * DD + k0 + gs * 8,
                        Ws + (size_t)(w * 32 + p * 8) * GBK);
        }
        __syncthreads();
        #pragma unroll
        for (int kk = 0; kk < 2; ++kk) {
            int ch = ((4 * kk + q) ^ (ln & 7)) * 8;
            half8v af[4], wf[4];
            #pragma unroll
            for (int mt = 0; mt < 4; ++mt)
                af[mt] = *(half8v*)&As[(wm * 64 + mt * 16 + ln) * GBK + ch];
            #pragma unroll
            for (int nt = 0; nt < 4; ++nt)
                wf[nt] = *(half8v*)&Ws[(wn * 64 + nt * 16 + ln) * GBK + ch];
            if (!isv) {
                #pragma unroll
                for (int mt = 0; mt < 4; ++mt)
                    #pragma unroll
                    for (int nt = 0; nt < 4; ++nt)
                        acc[mt][nt] = __builtin_amdgcn_mfma_f32_16x16x32_f16(
                            wf[nt], af[mt], acc[mt][nt], 0, 0, 0);  // C^T
            } else {
                #pragma unroll
                for (int mt = 0; mt < 4; ++mt)
                    #pragma unroll
                    for (int nt = 0; nt < 4; ++nt)
                        acc[mt][nt] = __builtin_amdgcn_mfma_f32_16x16x32_f16(
                            af[mt], wf[nt], acc[mt][nt], 0, 0, 0);  // C
            }
        }
        __syncthreads();
    }
    if (!isv) {
        _Float16* C = Call + (size_t)z * NE;
        #pragma unroll
        for (int mt = 0; mt < 4; ++mt) {
            int m = m0 + wm * 64 + mt * 16 + ln;
            int b = m >> 11, s = m & (SS - 1);
            #pragma unroll
            for (int nt = 0; nt < 4; ++nt) {
                int nb = n0 + wn * 64 + nt * 16 + q * 4;
                int h = nb >> 6, d0 = nb & 63;
                half4v pv = pack4(acc[mt][nt][0], acc[mt][nt][1],
                                  acc[mt][nt][2], acc[mt][nt][3]);
                *(half4v*)&C[((size_t)(b * HH + h) * SS + s) * HD + d0] = pv;
            }
        }
    } else {
        #pragma unroll
        for (int mt = 0; mt < 4; ++mt) {
            int mb = m0 + wm * 64 + mt * 16 + q * 4;
            int b = mb >> 11, s0 = mb & (SS - 1);
            #pragma unroll
            for (int nt = 0; nt < 4; ++nt) {
                int n = n0 + wn * 64 + nt * 16 + ln;
                int h = n >> 6, d = n & 63;
                half4v pv = pack4(acc[mt][nt][0], acc[mt][nt][1],
                                  acc[mt][nt][2], acc[mt][nt][3]);
                *(half4v*)&vtOut[((size_t)(b * HH + h) * HD + d) * SS + s0] = pv;
            }
        }
    }
}

// ---------------- Flash attention, S^T orientation, double-buffered --------
// 256 threads = 4 waves; each wave owns TWO 16-i columns (32 i rows).
// Rationale: Qt/Vs LDS fragment reads are identical across waves (broadcast),
// so fewer+fatter waves halve per-CU LDS traffic — the binding pipe.
// K-loop: ONE barrier per iter; next tile's global_load_lds issued right
// after the barrier so the next barrier's vmcnt(0) drain is ~free.
#define AI 128
#define AJ 64
__global__ __launch_bounds__(256, 2) void attn_mfma(const _Float16* __restrict__ qh,
                                                    const _Float16* __restrict__ kh,
                                                    const _Float16* __restrict__ vt,
                                                    float* __restrict__ out) {
    __shared__ __align__(16) _Float16 Qt[2][AJ * HD];   // 64 j x 64 d (swizzled)
    __shared__ __align__(16) _Float16 Vs[2][HD * AJ];   // 64 d x 64 j (swizzled)
    __shared__ __align__(16) _Float16 Ps[AI * AJ];      // wave-private P rows
    int t = threadIdx.x, w = t >> 6, lane = t & 63, q = lane >> 4, ln = lane & 15;
    int i0 = blockIdx.x * AI;
    int bh = blockIdx.y, b = bh >> 3, h = bh & 7;
    const _Float16* Kb = kh + (size_t)bh * SS * HD;
    const _Float16* Qb = qh + (size_t)bh * SS * HD;
    const _Float16* Vb = vt + (size_t)bh * HD * SS;

    // K fragments (B-operand): two i-cols per wave, iter-invariant, in regs
    half8v kf[2][2];
    #pragma unroll
    for (int c = 0; c < 2; ++c)
        #pragma unroll
        for (int kk = 0; kk < 2; ++kk)
            kf[c][kk] = *(const half8v*)&Kb[(size_t)(i0 + w * 32 + c * 16 + ln) * HD
                                            + kk * 32 + q * 8];

    f32x4 oacc[2][4], lacc[2];
    float m_run[2] = {-3.0e38f, -3.0e38f};
    lacc[0] = (f32x4){0.f, 0.f, 0.f, 0.f};
    lacc[1] = (f32x4){0.f, 0.f, 0.f, 0.f};
    #pragma unroll
    for (int c = 0; c < 2; ++c)
        #pragma unroll
        for (int mtd = 0; mtd < 4; ++mtd) oacc[c][mtd] = (f32x4){0.f, 0.f, 0.f, 0.f};
    half8v ones;
    #pragma unroll
    for (int e = 0; e < 8; ++e) ones[e] = (_Float16)1.0f;
    const f32x4 zf = (f32x4){0.f, 0.f, 0.f, 0.f};

    // staging: 256 threads stage 64x64 tiles in two 32-row rounds
    int sr = t >> 3;          // 0..31 (row, rounds add +32)
    int sc = t & 7;           // chunk slot
    int ssw = sc ^ (sr & 7);  // swizzled source chunk ((sr+32)&7 == sr&7)

    // prologue: stage tile 0 into buffer 0
    gload_lds16(Qb + (size_t)sr * HD + ssw * 8,        &Qt[0][w * 512]);
    gload_lds16(Qb + (size_t)(sr + 32) * HD + ssw * 8, &Qt[0][2048 + w * 512]);
    gload_lds16(Vb + (size_t)sr * SS + ssw * 8,        &Vs[0][w * 512]);
    gload_lds16(Vb + (size_t)(sr + 32) * SS + ssw * 8, &Vs[0][2048 + w * 512]);

    const int NITER = SS / AJ;
    for (int jt = 0; jt < NITER; ++jt) {
        int cur = jt & 1;
        __syncthreads();   // drains vmcnt -> buffer `cur` ready; prior reads done

        // prefetch next tile into the other buffer (in flight during compute)
        if (jt + 1 < NITER) {
            int j1 = (jt + 1) * AJ;
            gload_lds16(Qb + (size_t)(j1 + sr) * HD + ssw * 8,      &Qt[cur ^ 1][w * 512]);
            gload_lds16(Qb + (size_t)(j1 + sr + 32) * HD + ssw * 8, &Qt[cur ^ 1][2048 + w * 512]);
            gload_lds16(Vb + (size_t)sr * SS + j1 + ssw * 8,        &Vs[cur ^ 1][w * 512]);
            gload_lds16(Vb + (size_t)(sr + 32) * SS + j1 + ssw * 8, &Vs[cur ^ 1][2048 + w * 512]);
        }

        // ---- S^T = Q.K^T : M=j(64), N=i(2x16/wave), K=d(64) ----
        f32x4 sacc[2][4];
        __builtin_amdgcn_s_setprio(1);
        #pragma unroll
        for (int mt = 0; mt < 4; ++mt) {
            half8v qf = *(half8v*)&Qt[cur][(mt * 16 + ln) * HD + (q ^ (ln & 7)) * 8];
            sacc[0][mt] = __builtin_amdgcn_mfma_f32_16x16x32_f16(qf, kf[0][0], zf, 0, 0, 0);
            sacc[1][mt] = __builtin_amdgcn_mfma_f32_16x16x32_f16(qf, kf[1][0], zf, 0, 0, 0);
        }
        #pragma unroll
        for (int mt = 0; mt < 4; ++mt) {
            half8v qf = *(half8v*)&Qt[cur][(mt * 16 + ln) * HD + ((4 + q) ^ (ln & 7)) * 8];
            sacc[0][mt] = __builtin_amdgcn_mfma_f32_16x16x32_f16(qf, kf[0][1], sacc[0][mt], 0, 0, 0);
            sacc[1][mt] = __builtin_amdgcn_mfma_f32_16x16x32_f16(qf, kf[1][1], sacc[1][mt], 0, 0, 0);
        }
        __builtin_amdgcn_s_setprio(0);

        // ---- online softmax per i-col (16 local + 2 shuffles) ----
        #pragma unroll
        for (int c = 0; c < 2; ++c) {
            float mx = fmaxf(fmaxf(sacc[c][0][0], sacc[c][0][1]),
                             fmaxf(sacc[c][0][2], sacc[c][0][3]));
            #pragma unroll
            for (int mt = 1; mt < 4; ++mt) {
                float m2 = fmaxf(fmaxf(sacc[c][mt][0], sacc[c][mt][1]),
                                 fmaxf(sacc[c][mt][2], sacc[c][mt][3]));
                mx = fmaxf(mx, m2);
            }
            mx = fmaxf(mx, __shfl_xor(mx, 16));
            mx = fmaxf(mx, __shfl_xor(mx, 32));
            // defer-max (T13): only rescale when the max grew by > 7 (log2
            // domain; W1 is pre-scaled by log2e). P bounded by 2^7, fits f16;
            // O and l share the scale so it cancels in the epilogue divide.
            if (__any(mx > m_run[c] + 7.0f)) {
                float mn = fmaxf(m_run[c], mx);
                float a = fast_exp2(m_run[c] - mn);
                lacc[c] *= a;
                #pragma unroll
                for (int mtd = 0; mtd < 4; ++mtd) oacc[c][mtd] *= a;
                m_run[c] = mn;
            }
            float mcur = m_run[c];
            int rp = w * 32 + c * 16 + ln;
            #pragma unroll
            for (int mt = 0; mt < 4; ++mt) {
                float p0 = fast_exp2(sacc[c][mt][0] - mcur);
                float p1 = fast_exp2(sacc[c][mt][1] - mcur);
                float p2 = fast_exp2(sacc[c][mt][2] - mcur);
                float p3 = fast_exp2(sacc[c][mt][3] - mcur);
                int cw = mt * 2 + (q >> 1);
                int pos = cw ^ (ln & 7);
                *(half4v*)&Ps[(size_t)rp * AJ + pos * 8 + (q & 1) * 4] =
                    pack4(p0, p1, p2, p3);
            }
        }

        // ---- O^T += V^T.P^T ; l += 1.P^T  (M=d, N=i, K=j) ----
        __builtin_amdgcn_s_setprio(1);
        #pragma unroll
        for (int ks = 0; ks < 2; ++ks) {
            int pos = ((ks * 4 + q) ^ (ln & 7)) * 8;
            half8v pf0 = *(half8v*)&Ps[(size_t)(w * 32 + ln) * AJ + pos];
            half8v pf1 = *(half8v*)&Ps[(size_t)(w * 32 + 16 + ln) * AJ + pos];
            lacc[0] = __builtin_amdgcn_mfma_f32_16x16x32_f16(ones, pf0, lacc[0], 0, 0, 0);
            lacc[1] = __builtin_amdgcn_mfma_f32_16x16x32_f16(ones, pf1, lacc[1], 0, 0, 0);
            #pragma unroll
            for (int mtd = 0; mtd < 4; ++mtd) {
                half8v vf = *(half8v*)&Vs[cur][(size_t)(mtd * 16 + ln) * AJ + pos];
                oacc[0][mtd] = __builtin_amdgcn_mfma_f32_16x16x32_f16(vf, pf0, oacc[0][mtd], 0, 0, 0);
                oacc[1][mtd] = __builtin_amdgcn_mfma_f32_16x16x32_f16(vf, pf1, oacc[1][mtd], 0, 0, 0);
            }
        }
        __builtin_amdgcn_s_setprio(0);
    }

    // ---- epilogue: O[i][d] = O^T[d][i] / l ----
    #pragma unroll
    for (int c = 0; c < 2; ++c) {
        float inv = 1.0f / lacc[c][0];
        int i = i0 + w * 32 + c * 16 + ln;
        #pragma unroll
        for (int mtd = 0; mtd < 4; ++mtd) {
            float4 o;
            o.x = oacc[c][mtd][0] * inv;
            o.y = oacc[c][mtd][1] * inv;
            o.z = oacc[c][mtd][2] * inv;
            o.w = oacc[c][mtd][3] * inv;
            *(float4*)&out[(size_t)(b * SS + i) * DD + h * HD + mtd * 16 + q * 4] = o;
        }
    }
}

extern "C" void kernel_launch(void* const* d_in, const int* in_sizes, int n_in,
                              void* d_out, int out_size, void* d_ws, size_t ws_size,
                              hipStream_t stream) {
    const float* seq_k = (const float*)d_in[0];
    const float* seq_q = (const float*)d_in[1];
    const float* seq_v = (const float*)d_in[2];
    const float* W1    = (const float*)d_in[3];
    const float* W2    = (const float*)d_in[4];
    const float* W3    = (const float*)d_in[5];
    const float* gamma = (const float*)d_in[6];
    const float* beta  = (const float*)d_in[7];
    float* out = (float*)d_out;

    const size_t MB = 1024 * 1024;
    char* w8 = (char*)d_ws;
    float*    v_in = (float*)w8;                    // [0,16) MB fp32 residual
    _Float16* a16  = (_Float16*)(w8 + 16 * MB);     // q16,k16,v16 [16,40)
    _Float16* w16  = (_Float16*)(w8 + 40 * MB);     // [40,42)
    _Float16* qh   = (_Float16*)(w8 + 48 * MB);     // [48,56)
    _Float16* vt   = (_Float16*)(w8 + 64 * MB);     // [64,72)
    float*    ao   = (float*)(w8 + 16 * MB);        // aliases a16/w16 (dead post-gemm)

    _Float16* q16 = a16;                // q,k contiguous for fused cast
    _Float16* v16 = a16 + 2 * NE;
    _Float16* kh  = qh + NE;

    // 1. fused prep: LN(seq_v) + cast q/k + cast W (W1 pre-scaled by log2e)
    hipLaunchKernelGGL(prep_kernel, dim3(2 * NTOK + 768), dim3(256), 0, stream,
                       seq_v, seq_q, seq_k, W1, W2, W3, gamma, beta,
                       v_in, v16, q16, w16);
    // 2. projections: q,k -> head-split; v -> transposed vt directly
    hipLaunchKernelGGL(gemm_mfma, dim3(DD / GBN, NTOK / GBM, 3), dim3(256), 0, stream,
                       a16, w16, qh, vt);
    // 3. flash attention (double-buffered, 4 fat waves)
    hipLaunchKernelGGL(attn_mfma, dim3(SS / AI, BB * HH), dim3(256), 0, stream,
                       qh, kh, vt, ao);
    // 4. residual + final LN
    hipLaunchKernelGGL(ln_kernel, dim3(NTOK), dim3(256), 0, stream,
                       ao, v_in, gamma, beta, out);
}

// Round 2
// 201.719 us; speedup vs baseline: 1.0090x; 1.0090x over previous
//
#include <hip/hip_runtime.h>
#include <math.h>

#define BB 4
#define SS 2048
#define DD 512
#define HH 8
#define HD 64
#define NTOK (BB*SS)
#define EPS 1e-5f
#define NE ((size_t)NTOK * DD)
#define WN ((size_t)DD * DD)
#define LOG2E 1.4426950408889634f

typedef _Float16 half8v __attribute__((ext_vector_type(8)));
typedef _Float16 half4v __attribute__((ext_vector_type(4)));
typedef _Float16 half2v __attribute__((ext_vector_type(2)));
typedef float f32x4 __attribute__((ext_vector_type(4)));

__device__ __forceinline__ float fast_exp2(float x) {
#if __has_builtin(__builtin_amdgcn_exp2f)
    return __builtin_amdgcn_exp2f(x);
#else
    return __expf(x * 0.6931471805599453f);
#endif
}

__device__ __forceinline__ half2v pack2(float a, float b) {
    return __builtin_bit_cast(half2v, __builtin_amdgcn_cvt_pkrtz(a, b));
}

__device__ __forceinline__ half4v pack4(float a, float b, float c, float d) {
    half2v lo = pack2(a, b);
    half2v hi = pack2(c, d);
    half4v r; r[0] = lo[0]; r[1] = lo[1]; r[2] = hi[0]; r[3] = hi[1];
    return r;
}

__device__ __forceinline__ void gload_lds16(const void* g, void* l) {
    __builtin_amdgcn_global_load_lds(
        (const __attribute__((address_space(1))) unsigned int*)g,
        (__attribute__((address_space(3))) unsigned int*)l, 16, 0, 0);
}

// ---------------- final LayerNorm (with residual) ----------------
__global__ __launch_bounds__(256) void ln_kernel(const float* __restrict__ x,
                                                 const float* __restrict__ res,
                                                 const float* __restrict__ gamma,
                                                 const float* __restrict__ beta,
                                                 float* __restrict__ y) {
    int row = blockIdx.x;
    const float* xr = x + (size_t)row * DD;
    int t = threadIdx.x;
    float2 v = ((const float2*)xr)[t];
    {
        float2 r = ((const float2*)(res + (size_t)row * DD))[t];
        v.x += r.x; v.y += r.y;
    }
    float s = v.x + v.y;
    float ss = v.x * v.x + v.y * v.y;
    #pragma unroll
    for (int off = 32; off; off >>= 1) {
        s  += __shfl_down(s,  off);
        ss += __shfl_down(ss, off);
    }
    __shared__ float ws0[4], ws1[4];
    int wid = t >> 6, lane = t & 63;
    if (lane == 0) { ws0[wid] = s; ws1[wid] = ss; }
    __syncthreads();
    __shared__ float mu_s, rstd_s;
    if (t == 0) {
        float S0 = ws0[0] + ws0[1] + ws0[2] + ws0[3];
        float S1 = ws1[0] + ws1[1] + ws1[2] + ws1[3];
        float mu = S0 * (1.0f / DD);
        float var = S1 * (1.0f / DD) - mu * mu;
        mu_s = mu;
        rstd_s = rsqrtf(var + EPS);
    }
    __syncthreads();
    float mu = mu_s, rstd = rstd_s;
    float2 g = ((const float2*)gamma)[t];
    float2 bb = ((const float2*)beta)[t];
    float2 o;
    o.x = (v.x - mu) * rstd * g.x + bb.x;
    o.y = (v.y - mu) * rstd * g.y + bb.y;
    ((float2*)(y + (size_t)row * DD))[t] = o;
}

// ---------------- prep: LN(seq_v) + cast q/k + cast W (fused) --------------
__global__ __launch_bounds__(256) void prep_kernel(const float* __restrict__ seq_v,
                                                   const float* __restrict__ seq_q,
                                                   const float* __restrict__ seq_k,
                                                   const float* __restrict__ W1,
                                                   const float* __restrict__ W2,
                                                   const float* __restrict__ W3,
                                                   const float* __restrict__ gamma,
                                                   const float* __restrict__ beta,
                                                   float* __restrict__ v_in,
                                                   _Float16* __restrict__ v16,
                                                   _Float16* __restrict__ qk16,
                                                   _Float16* __restrict__ w16) {
    int bid = blockIdx.x;
    int t = threadIdx.x;
    if (bid < NTOK) {
        int row = bid;
        float2 v = ((const float2*)(seq_v + (size_t)row * DD))[t];
        float s = v.x + v.y;
        float ss = v.x * v.x + v.y * v.y;
        #pragma unroll
        for (int off = 32; off; off >>= 1) {
            s  += __shfl_down(s,  off);
            ss += __shfl_down(ss, off);
        }
        __shared__ float ws0[4], ws1[4];
        int wid = t >> 6, lane = t & 63;
        if (lane == 0) { ws0[wid] = s; ws1[wid] = ss; }
        __syncthreads();
        __shared__ float mu_s, rstd_s;
        if (t == 0) {
            float S0 = ws0[0] + ws0[1] + ws0[2] + ws0[3];
            float S1 = ws1[0] + ws1[1] + ws1[2] + ws1[3];
            float mu = S0 * (1.0f / DD);
            float var = S1 * (1.0f / DD) - mu * mu;
            mu_s = mu;
            rstd_s = rsqrtf(var + EPS);
        }
        __syncthreads();
        float mu = mu_s, rstd = rstd_s;
        float2 g = ((const float2*)gamma)[t];
        float2 bb = ((const float2*)beta)[t];
        float2 o;
        o.x = (v.x - mu) * rstd * g.x + bb.x;
        o.y = (v.y - mu) * rstd * g.y + bb.y;
        ((float2*)(v_in + (size_t)row * DD))[t] = o;
        *(half2v*)&v16[(size_t)row * DD + 2 * t] = pack2(o.x, o.y);
    } else if (bid < 2 * NTOK) {
        size_t i = ((size_t)(bid - NTOK) * 256 + t) * 4;
        const float* src = (i < NE) ? (seq_q + i) : (seq_k + (i - NE));
        float4 v = *(const float4*)src;
        *(half4v*)(qk16 + i) = pack4(v.x, v.y, v.z, v.w);
    } else {
        size_t i = ((size_t)(bid - 2 * NTOK) * 256 + t) * 4;
        const float* src; float sc;
        if (i < WN)          { src = W1 + i;            sc = LOG2E; }
        else if (i < 2 * WN) { src = W2 + (i - WN);     sc = 1.0f; }
        else                 { src = W3 + (i - 2 * WN); sc = 1.0f; }
        float4 v = *(const float4*)src;
        *(half4v*)(w16 + i) = pack4(v.x * sc, v.y * sc, v.z * sc, v.w * sc);
    }
}

// ---------------- MFMA GEMM: all three projections in one launch ------------
#define GBM 128
#define GBN 128
#define GBK 64
__global__ __launch_bounds__(256) void gemm_mfma(const _Float16* __restrict__ Aall,
                                                 const _Float16* __restrict__ Wall,
                                                 _Float16* __restrict__ Call,
                                                 _Float16* __restrict__ vtOut) {
    __shared__ __align__(16) _Float16 As[GBM * GBK];
    __shared__ __align__(16) _Float16 Ws[GBN * GBK];
    int z = blockIdx.z;
    bool isv = (z == 2);
    const _Float16* A = Aall + (size_t)z * NE;
    const _Float16* W = Wall + (size_t)z * WN;
    int t = threadIdx.x, w = t >> 6, lane = t & 63, q = lane >> 4, ln = lane & 15;
    int lrow = lane >> 3, lseg = lane & 7;
    int m0 = blockIdx.y * GBM, n0 = blockIdx.x * GBN;
    int wm = w & 1, wn = w >> 1;
    f32x4 acc[4][4];
    #pragma unroll
    for (int mt = 0; mt < 4; ++mt)
        #pragma unroll
        for (int nt = 0; nt < 4; ++nt)
            acc[mt][nt] = (f32x4){0.f, 0.f, 0.f, 0.f};

    int gs = lseg ^ lrow;
    for (int k0 = 0; k0 < DD; k0 += GBK) {
        #pragma unroll
        for (int p = 0; p < 4; ++p) {
            int r = w * 32 + p * 8 + lrow;
            gload_lds16(A + (size_t)(m0 + r) * DD + k0 + gs * 8,
                        As + (size_t)(w * 32 + p * 8) * GBK);
            gload_lds16(W + (size_t)(n0 + r) * DD + k0 + gs * 8,
                        Ws + (size_t)(w * 32 + p * 8) * GBK);
        }
        __syncthreads();
        #pragma unroll
        for (int kk = 0; kk < 2; ++kk) {
            int ch = ((4 * kk + q) ^ (ln & 7)) * 8;
            half8v af[4], wf[4];
            #pragma unroll
            for (int mt = 0; mt < 4; ++mt)
                af[mt] = *(half8v*)&As[(wm * 64 + mt * 16 + ln) * GBK + ch];
            #pragma unroll
            for (int nt = 0; nt < 4; ++nt)
                wf[nt] = *(half8v*)&Ws[(wn * 64 + nt * 16 + ln) * GBK + ch];
            if (!isv) {
                #pragma unroll
                for (int mt = 0; mt < 4; ++mt)
                    #pragma unroll
                    for (int nt = 0; nt < 4; ++nt)
                        acc[mt][nt] = __builtin_amdgcn_mfma_f32_16x16x32_f16(
                            wf[nt], af[mt], acc[mt][nt], 0, 0, 0);  // C^T
            } else {
                #pragma unroll
                for (int mt = 0; mt < 4; ++mt)
                    #pragma unroll
                    for (int nt = 0; nt < 4; ++nt)
                        acc[mt][nt] = __builtin_amdgcn_mfma_f32_16x16x32_f16(
                            af[mt], wf[nt], acc[mt][nt], 0, 0, 0);  // C
            }
        }
        __syncthreads();
    }
    if (!isv) {
        _Float16* C = Call + (size_t)z * NE;
        #pragma unroll
        for (int mt = 0; mt < 4; ++mt) {
            int m = m0 + wm * 64 + mt * 16 + ln;
            int b = m >> 11, s = m & (SS - 1);
            #pragma unroll
            for (int nt = 0; nt < 4; ++nt) {
                int nb = n0 + wn * 64 + nt * 16 + q * 4;
                int h = nb >> 6, d0 = nb & 63;
                half4v pv = pack4(acc[mt][nt][0], acc[mt][nt][1],
                                  acc[mt][nt][2], acc[mt][nt][3]);
                *(half4v*)&C[((size_t)(b * HH + h) * SS + s) * HD + d0] = pv;
            }
        }
    } else {
        #pragma unroll
        for (int mt = 0; mt < 4; ++mt) {
            int mb = m0 + wm * 64 + mt * 16 + q * 4;
            int b = mb >> 11, s0 = mb & (SS - 1);
            #pragma unroll
            for (int nt = 0; nt < 4; ++nt) {
                int n = n0 + wn * 64 + nt * 16 + ln;
                int h = n >> 6, d = n & 63;
                half4v pv = pack4(acc[mt][nt][0], acc[mt][nt][1],
                                  acc[mt][nt][2], acc[mt][nt][3]);
                *(half4v*)&vtOut[((size_t)(b * HH + h) * HD + d) * SS + s0] = pv;
            }
        }
    }
}

// ---------------- Flash attention, S^T orientation, software-pipelined -----
// 512 threads = 8 waves, 16 i-rows per wave (round-0 structure restored).
// New: 1-iter software pipeline. Q is TRIPLE-buffered; right after each
// barrier we issue next-next-tile stages and compute S(j+1)'s MFMAs (data
// already resident + drained), THEN run softmax(j) + PV(j). The S(j+1)
// cluster has no dependence on softmax(j), so the matrix pipe stays busy
// while the VALU does exp2/fmax — breaking the serial per-iter chain that
// held MfmaUtil at 24% / VALUBusy at 39%.
// XCD swizzle: 16 i-blocks of one (b,h) share full Q+V streams (512 KB);
// pinning 4 bh per XCD makes those streams L2-resident.
#define AI 128
#define AJ 64
__global__ __launch_bounds__(512, 4) void attn_mfma(const _Float16* __restrict__ qh,
                                                    const _Float16* __restrict__ kh,
                                                    const _Float16* __restrict__ vt,
                                                    float* __restrict__ out) {
    __shared__ __align__(16) _Float16 Qt[3][AJ * HD];   // 64 j x 64 d (swizzled), triple
    __shared__ __align__(16) _Float16 Vs[2][HD * AJ];   // 64 d x 64 j (swizzled), double
    __shared__ __align__(16) _Float16 Ps[AI * AJ];      // wave-private P rows
    int t = threadIdx.x, w = t >> 6, lane = t & 63, q = lane >> 4, ln = lane & 15;
    // XCD-aware swizzle of the flat 512-block grid: xcd = wg&7 (dispatch
    // round-robin); give each XCD 4 whole (b,h) with all 16 of their i-blocks.
    int wg = blockIdx.x;
    int slot = wg >> 3;
    int bh = (wg & 7) * 4 + (slot >> 4);
    int i0 = (slot & 15) * AI;
    int b = bh >> 3, h = bh & 7;
    const _Float16* Kb = kh + (size_t)bh * SS * HD;
    const _Float16* Qb = qh + (size_t)bh * SS * HD;
    const _Float16* Vb = vt + (size_t)bh * HD * SS;

    // K fragments (B-operand): row i = i0 + w*16 + ln, in regs for all j
    half8v kf[2];
    #pragma unroll
    for (int kk = 0; kk < 2; ++kk)
        kf[kk] = *(const half8v*)&Kb[(size_t)(i0 + w * 16 + ln) * HD + kk * 32 + q * 8];

    f32x4 oacc[4], lacc;
    float m_run = -3.0e38f;
    lacc = (f32x4){0.f, 0.f, 0.f, 0.f};
    #pragma unroll
    for (int mtd = 0; mtd < 4; ++mtd) oacc[mtd] = (f32x4){0.f, 0.f, 0.f, 0.f};
    half8v ones;
    #pragma unroll
    for (int e = 0; e < 8; ++e) ones[e] = (_Float16)1.0f;
    const f32x4 zf = (f32x4){0.f, 0.f, 0.f, 0.f};

    // staging: each thread stages one 16B chunk of Qt and one of Vs
    int sr = t >> 3;          // 0..63 (row)
    int sc = t & 7;           // chunk slot
    int ssw = sc ^ (sr & 7);  // swizzled source chunk

    // ---- prologue: tile 0 resident, tile 1 in flight, S(0) computed ----
    gload_lds16(Qb + (size_t)sr * HD + ssw * 8, &Qt[0][(size_t)w * 512]);
    gload_lds16(Vb + (size_t)sr * SS + ssw * 8, &Vs[0][(size_t)w * 512]);
    __syncthreads();   // drain: Q(0), V(0) resident
    gload_lds16(Qb + (size_t)(AJ + sr) * HD + ssw * 8, &Qt[1][(size_t)w * 512]);

    f32x4 sacc[4];
    #pragma unroll
    for (int mt = 0; mt < 4; ++mt) {
        half8v qf = *(half8v*)&Qt[0][(mt * 16 + ln) * HD + (q ^ (ln & 7)) * 8];
        sacc[mt] = __builtin_amdgcn_mfma_f32_16x16x32_f16(qf, kf[0], zf, 0, 0, 0);
    }
    #pragma unroll
    for (int mt = 0; mt < 4; ++mt) {
        half8v qf = *(half8v*)&Qt[0][(mt * 16 + ln) * HD + ((4 + q) ^ (ln & 7)) * 8];
        sacc[mt] = __builtin_amdgcn_mfma_f32_16x16x32_f16(qf, kf[1], sacc[mt], 0, 0, 0);
    }

    int rb = 1, sb = 2, vb = 0;   // read-next Q buf, stage Q buf, current V buf
    const int NITER = SS / AJ;
    for (int jt = 0; jt < NITER; ++jt) {
        __syncthreads();   // drains vmcnt/lgkm: Q(jt+1) resident; old buffers' readers done

        // stage Q(jt+2) and V(jt+1): one full iteration of slack to land
        if (jt + 2 < NITER)
            gload_lds16(Qb + (size_t)((jt + 2) * AJ + sr) * HD + ssw * 8,
                        &Qt[sb][(size_t)w * 512]);
        if (jt + 1 < NITER)
            gload_lds16(Vb + (size_t)sr * SS + (jt + 1) * AJ + ssw * 8,
                        &Vs[vb ^ 1][(size_t)w * 512]);

        // ---- S(jt+1) MFMAs now — independent of softmax(jt) below ----
        f32x4 snx[4] = {zf, zf, zf, zf};
        if (jt + 1 < NITER) {
            __builtin_amdgcn_s_setprio(1);
            #pragma unroll
            for (int mt = 0; mt < 4; ++mt) {
                half8v qf = *(half8v*)&Qt[rb][(mt * 16 + ln) * HD + (q ^ (ln & 7)) * 8];
                snx[mt] = __builtin_amdgcn_mfma_f32_16x16x32_f16(qf, kf[0], zf, 0, 0, 0);
            }
            #pragma unroll
            for (int mt = 0; mt < 4; ++mt) {
                half8v qf = *(half8v*)&Qt[rb][(mt * 16 + ln) * HD + ((4 + q) ^ (ln & 7)) * 8];
                snx[mt] = __builtin_amdgcn_mfma_f32_16x16x32_f16(qf, kf[1], snx[mt], 0, 0, 0);
            }
            __builtin_amdgcn_s_setprio(0);
        }

        // ---- online softmax over j for tile jt (overlaps S(jt+1) MFMAs) ----
        float mx = fmaxf(fmaxf(sacc[0][0], sacc[0][1]), fmaxf(sacc[0][2], sacc[0][3]));
        #pragma unroll
        for (int mt = 1; mt < 4; ++mt) {
            float m2 = fmaxf(fmaxf(sacc[mt][0], sacc[mt][1]),
                             fmaxf(sacc[mt][2], sacc[mt][3]));
            mx = fmaxf(mx, m2);
        }
        mx = fmaxf(mx, __shfl_xor(mx, 16));
        mx = fmaxf(mx, __shfl_xor(mx, 32));
        // defer-max (T13): rescale only when max grew by >7 (log2 domain;
        // W1 pre-scaled by log2e). P bounded by 2^7, fits f16; the common
        // scale cancels in the epilogue divide.
        if (__any(mx > m_run + 7.0f)) {
            float mn = fmaxf(m_run, mx);
            float a = fast_exp2(m_run - mn);
            lacc *= a;
            #pragma unroll
            for (int mtd = 0; mtd < 4; ++mtd) oacc[mtd] *= a;
            m_run = mn;
        }
        int rp = w * 16 + ln;
        #pragma unroll
        for (int mt = 0; mt < 4; ++mt) {
            float p0 = fast_exp2(sacc[mt][0] - m_run);
            float p1 = fast_exp2(sacc[mt][1] - m_run);
            float p2 = fast_exp2(sacc[mt][2] - m_run);
            float p3 = fast_exp2(sacc[mt][3] - m_run);
            int cw = mt * 2 + (q >> 1);
            int pos = cw ^ (ln & 7);
            *(half4v*)&Ps[(size_t)rp * AJ + pos * 8 + (q & 1) * 4] =
                pack4(p0, p1, p2, p3);
        }

        // ---- O^T += V^T.P^T ; l += 1.P^T  (M=d, N=i, K=j) ----
        __builtin_amdgcn_s_setprio(1);
        #pragma unroll
        for (int ks = 0; ks < 2; ++ks) {
            int pos = ((ks * 4 + q) ^ (ln & 7)) * 8;
            half8v pf = *(half8v*)&Ps[(size_t)(w * 16 + ln) * AJ + pos];
            lacc = __builtin_amdgcn_mfma_f32_16x16x32_f16(ones, pf, lacc, 0, 0, 0);
            #pragma unroll
            for (int mtd = 0; mtd < 4; ++mtd) {
                half8v vf = *(half8v*)&Vs[vb][(size_t)(mtd * 16 + ln) * AJ + pos];
                oacc[mtd] = __builtin_amdgcn_mfma_f32_16x16x32_f16(vf, pf, oacc[mtd], 0, 0, 0);
            }
        }
        __builtin_amdgcn_s_setprio(0);

        // rotate pipeline state
        #pragma unroll
        for (int mt = 0; mt < 4; ++mt) sacc[mt] = snx[mt];
        rb = (rb == 2) ? 0 : rb + 1;
        sb = (sb == 2) ? 0 : sb + 1;
        vb ^= 1;
    }

    // ---- epilogue: O[i][d] = O^T[d][i] / l ----
    float inv = 1.0f / lacc[0];
    int i = i0 + w * 16 + ln;
    #pragma unroll
    for (int mtd = 0; mtd < 4; ++mtd) {
        float4 o;
        o.x = oacc[mtd][0] * inv;
        o.y = oacc[mtd][1] * inv;
        o.z = oacc[mtd][2] * inv;
        o.w = oacc[mtd][3] * inv;
        *(float4*)&out[(size_t)(b * SS + i) * DD + h * HD + mtd * 16 + q * 4] = o;
    }
}

extern "C" void kernel_launch(void* const* d_in, const int* in_sizes, int n_in,
                              void* d_out, int out_size, void* d_ws, size_t ws_size,
                              hipStream_t stream) {
    const float* seq_k = (const float*)d_in[0];
    const float* seq_q = (const float*)d_in[1];
    const float* seq_v = (const float*)d_in[2];
    const float* W1    = (const float*)d_in[3];
    const float* W2    = (const float*)d_in[4];
    const float* W3    = (const float*)d_in[5];
    const float* gamma = (const float*)d_in[6];
    const float* beta  = (const float*)d_in[7];
    float* out = (float*)d_out;

    const size_t MB = 1024 * 1024;
    char* w8 = (char*)d_ws;
    float*    v_in = (float*)w8;                    // [0,16) MB fp32 residual
    _Float16* a16  = (_Float16*)(w8 + 16 * MB);     // q16,k16,v16 [16,40)
    _Float16* w16  = (_Float16*)(w8 + 40 * MB);     // [40,42)
    _Float16* qh   = (_Float16*)(w8 + 48 * MB);     // [48,56)
    _Float16* vt   = (_Float16*)(w8 + 64 * MB);     // [64,72)
    float*    ao   = (float*)(w8 + 16 * MB);        // aliases a16/w16 (dead post-gemm)

    _Float16* q16 = a16;                // q,k contiguous for fused cast
    _Float16* v16 = a16 + 2 * NE;
    _Float16* kh  = qh + NE;

    // 1. fused prep: LN(seq_v) + cast q/k + cast W (W1 pre-scaled by log2e)
    hipLaunchKernelGGL(prep_kernel, dim3(2 * NTOK + 768), dim3(256), 0, stream,
                       seq_v, seq_q, seq_k, W1, W2, W3, gamma, beta,
                       v_in, v16, q16, w16);
    // 2. projections: q,k -> head-split; v -> transposed vt directly
    hipLaunchKernelGGL(gemm_mfma, dim3(DD / GBN, NTOK / GBM, 3), dim3(256), 0, stream,
                       a16, w16, qh, vt);
    // 3. flash attention (software-pipelined, 8 waves, XCD-swizzled)
    hipLaunchKernelGGL(attn_mfma, dim3((SS / AI) * BB * HH), dim3(512), 0, stream,
                       qh, kh, vt, ao);
    // 4. residual + final LN
    hipLaunchKernelGGL(ln_kernel, dim3(NTOK), dim3(256), 0, stream,
                       ao, v_in, gamma, beta, out);
}

// Round 3
// 197.900 us; speedup vs baseline: 1.0285x; 1.0193x over previous
//
#include <hip/hip_runtime.h>
#include <math.h>

#define BB 4
#define SS 2048
#define DD 512
#define HH 8
#define HD 64
#define NTOK (BB*SS)
#define EPS 1e-5f
#define NE ((size_t)NTOK * DD)
#define WN ((size_t)DD * DD)
#define LOG2E 1.4426950408889634f

typedef _Float16 half8v __attribute__((ext_vector_type(8)));
typedef _Float16 half4v __attribute__((ext_vector_type(4)));
typedef _Float16 half2v __attribute__((ext_vector_type(2)));
typedef float f32x4 __attribute__((ext_vector_type(4)));

__device__ __forceinline__ float fast_exp2(float x) {
#if __has_builtin(__builtin_amdgcn_exp2f)
    return __builtin_amdgcn_exp2f(x);
#else
    return __expf(x * 0.6931471805599453f);
#endif
}

__device__ __forceinline__ half2v pack2(float a, float b) {
    return __builtin_bit_cast(half2v, __builtin_amdgcn_cvt_pkrtz(a, b));
}

__device__ __forceinline__ half4v pack4(float a, float b, float c, float d) {
    half2v lo = pack2(a, b);
    half2v hi = pack2(c, d);
    half4v r; r[0] = lo[0]; r[1] = lo[1]; r[2] = hi[0]; r[3] = hi[1];
    return r;
}

__device__ __forceinline__ void gload_lds16(const void* g, void* l) {
    __builtin_amdgcn_global_load_lds(
        (const __attribute__((address_space(1))) unsigned int*)g,
        (__attribute__((address_space(3))) unsigned int*)l, 16, 0, 0);
}

// ---------------- final LayerNorm (with residual) ----------------
__global__ __launch_bounds__(256) void ln_kernel(const float* __restrict__ x,
                                                 const float* __restrict__ res,
                                                 const float* __restrict__ gamma,
                                                 const float* __restrict__ beta,
                                                 float* __restrict__ y) {
    int row = blockIdx.x;
    const float* xr = x + (size_t)row * DD;
    int t = threadIdx.x;
    float2 v = ((const float2*)xr)[t];
    {
        float2 r = ((const float2*)(res + (size_t)row * DD))[t];
        v.x += r.x; v.y += r.y;
    }
    float s = v.x + v.y;
    float ss = v.x * v.x + v.y * v.y;
    #pragma unroll
    for (int off = 32; off; off >>= 1) {
        s  += __shfl_down(s,  off);
        ss += __shfl_down(ss, off);
    }
    __shared__ float ws0[4], ws1[4];
    int wid = t >> 6, lane = t & 63;
    if (lane == 0) { ws0[wid] = s; ws1[wid] = ss; }
    __syncthreads();
    __shared__ float mu_s, rstd_s;
    if (t == 0) {
        float S0 = ws0[0] + ws0[1] + ws0[2] + ws0[3];
        float S1 = ws1[0] + ws1[1] + ws1[2] + ws1[3];
        float mu = S0 * (1.0f / DD);
        float var = S1 * (1.0f / DD) - mu * mu;
        mu_s = mu;
        rstd_s = rsqrtf(var + EPS);
    }
    __syncthreads();
    float mu = mu_s, rstd = rstd_s;
    float2 g = ((const float2*)gamma)[t];
    float2 bb = ((const float2*)beta)[t];
    float2 o;
    o.x = (v.x - mu) * rstd * g.x + bb.x;
    o.y = (v.y - mu) * rstd * g.y + bb.y;
    ((float2*)(y + (size_t)row * DD))[t] = o;
}

// ---------------- prep: LN(seq_v) + cast q/k + cast W (fused) --------------
__global__ __launch_bounds__(256) void prep_kernel(const float* __restrict__ seq_v,
                                                   const float* __restrict__ seq_q,
                                                   const float* __restrict__ seq_k,
                                                   const float* __restrict__ W1,
                                                   const float* __restrict__ W2,
                                                   const float* __restrict__ W3,
                                                   const float* __restrict__ gamma,
                                                   const float* __restrict__ beta,
                                                   float* __restrict__ v_in,
                                                   _Float16* __restrict__ v16,
                                                   _Float16* __restrict__ qk16,
                                                   _Float16* __restrict__ w16) {
    int bid = blockIdx.x;
    int t = threadIdx.x;
    if (bid < NTOK) {
        int row = bid;
        float2 v = ((const float2*)(seq_v + (size_t)row * DD))[t];
        float s = v.x + v.y;
        float ss = v.x * v.x + v.y * v.y;
        #pragma unroll
        for (int off = 32; off; off >>= 1) {
            s  += __shfl_down(s,  off);
            ss += __shfl_down(ss, off);
        }
        __shared__ float ws0[4], ws1[4];
        int wid = t >> 6, lane = t & 63;
        if (lane == 0) { ws0[wid] = s; ws1[wid] = ss; }
        __syncthreads();
        __shared__ float mu_s, rstd_s;
        if (t == 0) {
            float S0 = ws0[0] + ws0[1] + ws0[2] + ws0[3];
            float S1 = ws1[0] + ws1[1] + ws1[2] + ws1[3];
            float mu = S0 * (1.0f / DD);
            float var = S1 * (1.0f / DD) - mu * mu;
            mu_s = mu;
            rstd_s = rsqrtf(var + EPS);
        }
        __syncthreads();
        float mu = mu_s, rstd = rstd_s;
        float2 g = ((const float2*)gamma)[t];
        float2 bb = ((const float2*)beta)[t];
        float2 o;
        o.x = (v.x - mu) * rstd * g.x + bb.x;
        o.y = (v.y - mu) * rstd * g.y + bb.y;
        ((float2*)(v_in + (size_t)row * DD))[t] = o;
        *(half2v*)&v16[(size_t)row * DD + 2 * t] = pack2(o.x, o.y);
    } else if (bid < 2 * NTOK) {
        size_t i = ((size_t)(bid - NTOK) * 256 + t) * 4;
        const float* src = (i < NE) ? (seq_q + i) : (seq_k + (i - NE));
        float4 v = *(const float4*)src;
        *(half4v*)(qk16 + i) = pack4(v.x, v.y, v.z, v.w);
    } else {
        size_t i = ((size_t)(bid - 2 * NTOK) * 256 + t) * 4;
        const float* src; float sc;
        if (i < WN)          { src = W1 + i;            sc = LOG2E; }
        else if (i < 2 * WN) { src = W2 + (i - WN);     sc = 1.0f; }
        else                 { src = W3 + (i - 2 * WN); sc = 1.0f; }
        float4 v = *(const float4*)src;
        *(half4v*)(w16 + i) = pack4(v.x * sc, v.y * sc, v.z * sc, v.w * sc);
    }
}

// ---------------- MFMA GEMM: all three projections in one launch ------------
// Epilogue rework: accumulators are staged into a swizzled 128x128 f16 LDS
// tile (reusing the As/Ws space) and stored back fully coalesced (16B runs,
// 128-256B contiguous per row). The old direct store scattered 8B at
// 128B..4KB stride (12.5-50% store efficiency) — the dominant gemm cost.
#define GBM 128
#define GBN 128
#define GBK 64
__global__ __launch_bounds__(256) void gemm_mfma(const _Float16* __restrict__ Aall,
                                                 const _Float16* __restrict__ Wall,
                                                 _Float16* __restrict__ Call,
                                                 _Float16* __restrict__ vtOut) {
    __shared__ __align__(16) _Float16 smem[GBM * GBN];   // 32KB, reused by epilogue
    _Float16* As = smem;                    // [GBM*GBK) staging
    _Float16* Ws = smem + (size_t)GBM * GBK;
    int z = blockIdx.z;
    bool isv = (z == 2);
    const _Float16* A = Aall + (size_t)z * NE;
    const _Float16* W = Wall + (size_t)z * WN;
    int t = threadIdx.x, w = t >> 6, lane = t & 63, q = lane >> 4, ln = lane & 15;
    int lrow = lane >> 3, lseg = lane & 7;
    int m0 = blockIdx.y * GBM, n0 = blockIdx.x * GBN;
    int wm = w & 1, wn = w >> 1;
    f32x4 acc[4][4];
    #pragma unroll
    for (int mt = 0; mt < 4; ++mt)
        #pragma unroll
        for (int nt = 0; nt < 4; ++nt)
            acc[mt][nt] = (f32x4){0.f, 0.f, 0.f, 0.f};

    int gs = lseg ^ lrow;
    for (int k0 = 0; k0 < DD; k0 += GBK) {
        #pragma unroll
        for (int p = 0; p < 4; ++p) {
            int r = w * 32 + p * 8 + lrow;
            gload_lds16(A + (size_t)(m0 + r) * DD + k0 + gs * 8,
                        As + (size_t)(w * 32 + p * 8) * GBK);
            gload_lds16(W + (size_t)(n0 + r) * DD + k0 + gs * 8,
                        Ws + (size_t)(w * 32 + p * 8) * GBK);
        }
        __syncthreads();
        #pragma unroll
        for (int kk = 0; kk < 2; ++kk) {
            int ch = ((4 * kk + q) ^ (ln & 7)) * 8;
            half8v af[4], wf[4];
            #pragma unroll
            for (int mt = 0; mt < 4; ++mt)
                af[mt] = *(half8v*)&As[(wm * 64 + mt * 16 + ln) * GBK + ch];
            #pragma unroll
            for (int nt = 0; nt < 4; ++nt)
                wf[nt] = *(half8v*)&Ws[(wn * 64 + nt * 16 + ln) * GBK + ch];
            if (!isv) {
                #pragma unroll
                for (int mt = 0; mt < 4; ++mt)
                    #pragma unroll
                    for (int nt = 0; nt < 4; ++nt)
                        acc[mt][nt] = __builtin_amdgcn_mfma_f32_16x16x32_f16(
                            wf[nt], af[mt], acc[mt][nt], 0, 0, 0);  // C^T
            } else {
                #pragma unroll
                for (int mt = 0; mt < 4; ++mt)
                    #pragma unroll
                    for (int nt = 0; nt < 4; ++nt)
                        acc[mt][nt] = __builtin_amdgcn_mfma_f32_16x16x32_f16(
                            af[mt], wf[nt], acc[mt][nt], 0, 0, 0);  // C
            }
        }
        __syncthreads();
    }

    // ---- epilogue: stage 128x128 f16 tile in LDS (16B-chunk XOR swizzle),
    //      then fully-coalesced 16B stores. row = outer (token for q/k, d for
    //      v); inner = contiguous-memory axis. acc's 4 values lie along inner.
    if (!isv) {
        #pragma unroll
        for (int mt = 0; mt < 4; ++mt) {
            int mloc = wm * 64 + mt * 16 + ln;            // token-local row
            #pragma unroll
            for (int nt = 0; nt < 4; ++nt) {
                int nloc = wn * 64 + nt * 16 + q * 4;     // d-local col
                int cs = (nloc >> 3) ^ (mloc & 7);
                char* p = (char*)smem + mloc * 256 + cs * 16 + (nloc & 7) * 2;
                *(half4v*)p = pack4(acc[mt][nt][0], acc[mt][nt][1],
                                    acc[mt][nt][2], acc[mt][nt][3]);
            }
        }
    } else {
        #pragma unroll
        for (int nt = 0; nt < 4; ++nt) {
            int dloc = wn * 64 + nt * 16 + ln;            // d-local row
            #pragma unroll
            for (int mt = 0; mt < 4; ++mt) {
                int sloc = wm * 64 + mt * 16 + q * 4;     // token-local col
                int cs = (sloc >> 3) ^ (dloc & 7);
                char* p = (char*)smem + dloc * 256 + cs * 16 + (sloc & 7) * 2;
                *(half4v*)p = pack4(acc[mt][nt][0], acc[mt][nt][1],
                                    acc[mt][nt][2], acc[mt][nt][3]);
            }
        }
    }
    __syncthreads();
    int bq = m0 >> 11, sbase = m0 & (SS - 1);   // block never crosses a batch
    if (!isv) {
        _Float16* C = Call + (size_t)z * NE;
        #pragma unroll
        for (int p = 0; p < 8; ++p) {
            int id = p * 256 + t;                 // 0..2047
            int r = id >> 4, c = id & 15;         // token row, d-chunk
            half8v vv = *(half8v*)((char*)smem + r * 256 + ((c ^ (r & 7)) * 16));
            int n = n0 + c * 8;
            int h = n >> 6, d0 = n & 63;
            *(half8v*)&C[((size_t)(bq * HH + h) * SS + (sbase + r)) * HD + d0] = vv;
        }
    } else {
        #pragma unroll
        for (int p = 0; p < 8; ++p) {
            int id = p * 256 + t;
            int r = id >> 4, c = id & 15;         // d row, token chunk
            half8v vv = *(half8v*)((char*)smem + r * 256 + ((c ^ (r & 7)) * 16));
            int d = n0 + r;
            int h = d >> 6, dd = d & 63;
            *(half8v*)&vtOut[((size_t)(bq * HH + h) * HD + dd) * SS + sbase + c * 8] = vv;
        }
    }
}

// ---------------- Flash attention, S^T orientation, double-buffered --------
// Round-0 body (known-good 62us): 512 threads = 8 waves, 16 i-rows per wave.
// Per rounds 1-2: the kernel is SIMD-issue-bound (VALU 46% + MFMA 24%);
// occupancy and S-pipelining are not levers. Kept: XCD swizzle (FETCH 5.7x
// lower), setprio around MFMA clusters, defer-max threshold.
#define AI 128
#define AJ 64
__global__ __launch_bounds__(512, 4) void attn_mfma(const _Float16* __restrict__ qh,
                                                    const _Float16* __restrict__ kh,
                                                    const _Float16* __restrict__ vt,
                                                    float* __restrict__ out) {
    __shared__ __align__(16) _Float16 Qt[2][AJ * HD];   // 64 j x 64 d (swizzled)
    __shared__ __align__(16) _Float16 Vs[2][HD * AJ];   // 64 d x 64 j (swizzled)
    __shared__ __align__(16) _Float16 Ps[AI * AJ];      // wave-private P rows
    int t = threadIdx.x, w = t >> 6, lane = t & 63, q = lane >> 4, ln = lane & 15;
    // XCD-aware swizzle: xcd = wg&7 (round-robin dispatch); each XCD owns 4
    // whole (b,h) so their Q+V streams stay L2-resident across 16 i-blocks.
    int wg = blockIdx.x;
    int slot = wg >> 3;
    int bh = (wg & 7) * 4 + (slot >> 4);
    int i0 = (slot & 15) * AI;
    int b = bh >> 3, h = bh & 7;
    const _Float16* Kb = kh + (size_t)bh * SS * HD;
    const _Float16* Qb = qh + (size_t)bh * SS * HD;
    const _Float16* Vb = vt + (size_t)bh * HD * SS;

    // K fragments (B-operand): row i = i0 + w*16 + ln, in regs for all j
    half8v kf[2];
    #pragma unroll
    for (int kk = 0; kk < 2; ++kk)
        kf[kk] = *(const half8v*)&Kb[(size_t)(i0 + w * 16 + ln) * HD + kk * 32 + q * 8];

    f32x4 oacc[4], lacc;
    float m_run = -3.0e38f;
    lacc = (f32x4){0.f, 0.f, 0.f, 0.f};
    #pragma unroll
    for (int mtd = 0; mtd < 4; ++mtd) oacc[mtd] = (f32x4){0.f, 0.f, 0.f, 0.f};
    half8v ones;
    #pragma unroll
    for (int e = 0; e < 8; ++e) ones[e] = (_Float16)1.0f;
    const f32x4 zf = (f32x4){0.f, 0.f, 0.f, 0.f};

    // staging: each thread stages one 16B chunk of Qt and one of Vs
    int sr = t >> 3;          // 0..63 (row)
    int sc = t & 7;           // chunk slot
    int ssw = sc ^ (sr & 7);  // swizzled source chunk

    // prologue: stage tile 0 into buffer 0
    gload_lds16(Qb + (size_t)sr * HD + ssw * 8, &Qt[0][(size_t)w * 512]);
    gload_lds16(Vb + (size_t)sr * SS + ssw * 8, &Vs[0][(size_t)w * 512]);

    const int NITER = SS / AJ;
    for (int jt = 0; jt < NITER; ++jt) {
        int cur = jt & 1;
        __syncthreads();   // drains vmcnt -> buffer `cur` ready; prior reads done

        // prefetch next tile into the other buffer (in flight during compute)
        if (jt + 1 < NITER) {
            int j1 = (jt + 1) * AJ;
            gload_lds16(Qb + (size_t)(j1 + sr) * HD + ssw * 8, &Qt[cur ^ 1][(size_t)w * 512]);
            gload_lds16(Vb + (size_t)sr * SS + j1 + ssw * 8,   &Vs[cur ^ 1][(size_t)w * 512]);
        }

        // ---- S^T = Q.K^T : M=j(64), N=i(16/wave), K=d(64) ----
        f32x4 sacc[4];
        __builtin_amdgcn_s_setprio(1);
        #pragma unroll
        for (int mt = 0; mt < 4; ++mt) {
            half8v qf = *(half8v*)&Qt[cur][(mt * 16 + ln) * HD + (q ^ (ln & 7)) * 8];
            sacc[mt] = __builtin_amdgcn_mfma_f32_16x16x32_f16(qf, kf[0], zf, 0, 0, 0);
        }
        #pragma unroll
        for (int mt = 0; mt < 4; ++mt) {
            half8v qf = *(half8v*)&Qt[cur][(mt * 16 + ln) * HD + ((4 + q) ^ (ln & 7)) * 8];
            sacc[mt] = __builtin_amdgcn_mfma_f32_16x16x32_f16(qf, kf[1], sacc[mt], 0, 0, 0);
        }
        __builtin_amdgcn_s_setprio(0);

        // ---- online softmax over j (16 local + 2 shuffles) ----
        float mx = fmaxf(fmaxf(sacc[0][0], sacc[0][1]), fmaxf(sacc[0][2], sacc[0][3]));
        #pragma unroll
        for (int mt = 1; mt < 4; ++mt) {
            float m2 = fmaxf(fmaxf(sacc[mt][0], sacc[mt][1]),
                             fmaxf(sacc[mt][2], sacc[mt][3]));
            mx = fmaxf(mx, m2);
        }
        mx = fmaxf(mx, __shfl_xor(mx, 16));
        mx = fmaxf(mx, __shfl_xor(mx, 32));
        // defer-max (T13): rescale only when max grew by >7 (log2 domain;
        // W1 pre-scaled by log2e). P bounded by 2^7, fits f16; the common
        // scale cancels in the epilogue divide.
        if (__any(mx > m_run + 7.0f)) {
            float mn = fmaxf(m_run, mx);
            float a = fast_exp2(m_run - mn);
            lacc *= a;
            #pragma unroll
            for (int mtd = 0; mtd < 4; ++mtd) oacc[mtd] *= a;
            m_run = mn;
        }

        // ---- P = exp2(S^T - m) -> wave-private LDS rows (no barrier) ----
        int rp = w * 16 + ln;
        #pragma unroll
        for (int mt = 0; mt < 4; ++mt) {
            float p0 = fast_exp2(sacc[mt][0] - m_run);
            float p1 = fast_exp2(sacc[mt][1] - m_run);
            float p2 = fast_exp2(sacc[mt][2] - m_run);
            float p3 = fast_exp2(sacc[mt][3] - m_run);
            int cw = mt * 2 + (q >> 1);
            int pos = cw ^ (ln & 7);
            *(half4v*)&Ps[(size_t)rp * AJ + pos * 8 + (q & 1) * 4] =
                pack4(p0, p1, p2, p3);
        }

        // ---- O^T += V^T.P^T ; l += 1.P^T  (M=d, N=i, K=j) ----
        __builtin_amdgcn_s_setprio(1);
        #pragma unroll
        for (int ks = 0; ks < 2; ++ks) {
            int pos = ((ks * 4 + q) ^ (ln & 7)) * 8;
            half8v pf = *(half8v*)&Ps[(size_t)(w * 16 + ln) * AJ + pos];
            lacc = __builtin_amdgcn_mfma_f32_16x16x32_f16(ones, pf, lacc, 0, 0, 0);
            #pragma unroll
            for (int mtd = 0; mtd < 4; ++mtd) {
                half8v vf = *(half8v*)&Vs[cur][(size_t)(mtd * 16 + ln) * AJ + pos];
                oacc[mtd] = __builtin_amdgcn_mfma_f32_16x16x32_f16(vf, pf, oacc[mtd], 0, 0, 0);
            }
        }
        __builtin_amdgcn_s_setprio(0);
    }

    // ---- epilogue: O[i][d] = O^T[d][i] / l ----
    float inv = 1.0f / lacc[0];
    int i = i0 + w * 16 + ln;
    #pragma unroll
    for (int mtd = 0; mtd < 4; ++mtd) {
        float4 o;
        o.x = oacc[mtd][0] * inv;
        o.y = oacc[mtd][1] * inv;
        o.z = oacc[mtd][2] * inv;
        o.w = oacc[mtd][3] * inv;
        *(float4*)&out[(size_t)(b * SS + i) * DD + h * HD + mtd * 16 + q * 4] = o;
    }
}

extern "C" void kernel_launch(void* const* d_in, const int* in_sizes, int n_in,
                              void* d_out, int out_size, void* d_ws, size_t ws_size,
                              hipStream_t stream) {
    const float* seq_k = (const float*)d_in[0];
    const float* seq_q = (const float*)d_in[1];
    const float* seq_v = (const float*)d_in[2];
    const float* W1    = (const float*)d_in[3];
    const float* W2    = (const float*)d_in[4];
    const float* W3    = (const float*)d_in[5];
    const float* gamma = (const float*)d_in[6];
    const float* beta  = (const float*)d_in[7];
    float* out = (float*)d_out;

    const size_t MB = 1024 * 1024;
    char* w8 = (char*)d_ws;
    float*    v_in = (float*)w8;                    // [0,16) MB fp32 residual
    _Float16* a16  = (_Float16*)(w8 + 16 * MB);     // q16,k16,v16 [16,40)
    _Float16* w16  = (_Float16*)(w8 + 40 * MB);     // [40,42)
    _Float16* qh   = (_Float16*)(w8 + 48 * MB);     // [48,56)
    _Float16* vt   = (_Float16*)(w8 + 64 * MB);     // [64,72)
    float*    ao   = (float*)(w8 + 16 * MB);        // aliases a16/w16 (dead post-gemm)

    _Float16* q16 = a16;                // q,k contiguous for fused cast
    _Float16* v16 = a16 + 2 * NE;
    _Float16* kh  = qh + NE;

    // 1. fused prep: LN(seq_v) + cast q/k + cast W (W1 pre-scaled by log2e)
    hipLaunchKernelGGL(prep_kernel, dim3(2 * NTOK + 768), dim3(256), 0, stream,
                       seq_v, seq_q, seq_k, W1, W2, W3, gamma, beta,
                       v_in, v16, q16, w16);
    // 2. projections: q,k -> head-split; v -> transposed vt (coalesced epilogue)
    hipLaunchKernelGGL(gemm_mfma, dim3(DD / GBN, NTOK / GBM, 3), dim3(256), 0, stream,
                       a16, w16, qh, vt);
    // 3. flash attention (double-buffered, XCD-swizzled)
    hipLaunchKernelGGL(attn_mfma, dim3((SS / AI) * BB * HH), dim3(512), 0, stream,
                       qh, kh, vt, ao);
    // 4. residual + final LN
    hipLaunchKernelGGL(ln_kernel, dim3(NTOK), dim3(256), 0, stream,
                       ao, v_in, gamma, beta, out);
}

// Round 4
// 184.197 us; speedup vs baseline: 1.1050x; 1.0744x over previous
//
#include <hip/hip_runtime.h>
#include <math.h>

#define BB 4
#define SS 2048
#define DD 512
#define HH 8
#define HD 64
#define NTOK (BB*SS)
#define EPS 1e-5f
#define NE ((size_t)NTOK * DD)
#define WN ((size_t)DD * DD)
#define LOG2E 1.4426950408889634f

typedef _Float16 half8v __attribute__((ext_vector_type(8)));
typedef _Float16 half4v __attribute__((ext_vector_type(4)));
typedef _Float16 half2v __attribute__((ext_vector_type(2)));
typedef float f32x4 __attribute__((ext_vector_type(4)));

__device__ __forceinline__ float fast_exp2(float x) {
#if __has_builtin(__builtin_amdgcn_exp2f)
    return __builtin_amdgcn_exp2f(x);
#else
    return __expf(x * 0.6931471805599453f);
#endif
}

__device__ __forceinline__ half2v pack2(float a, float b) {
    return __builtin_bit_cast(half2v, __builtin_amdgcn_cvt_pkrtz(a, b));
}

__device__ __forceinline__ half4v pack4(float a, float b, float c, float d) {
    half2v lo = pack2(a, b);
    half2v hi = pack2(c, d);
    half4v r; r[0] = lo[0]; r[1] = lo[1]; r[2] = hi[0]; r[3] = hi[1];
    return r;
}

__device__ __forceinline__ void gload_lds16(const void* g, void* l) {
    __builtin_amdgcn_global_load_lds(
        (const __attribute__((address_space(1))) unsigned int*)g,
        (__attribute__((address_space(3))) unsigned int*)l, 16, 0, 0);
}

// ---------------- final LayerNorm (with residual) ----------------
__global__ __launch_bounds__(256) void ln_kernel(const float* __restrict__ x,
                                                 const float* __restrict__ res,
                                                 const float* __restrict__ gamma,
                                                 const float* __restrict__ beta,
                                                 float* __restrict__ y) {
    int row = blockIdx.x;
    const float* xr = x + (size_t)row * DD;
    int t = threadIdx.x;
    float2 v = ((const float2*)xr)[t];
    {
        float2 r = ((const float2*)(res + (size_t)row * DD))[t];
        v.x += r.x; v.y += r.y;
    }
    float s = v.x + v.y;
    float ss = v.x * v.x + v.y * v.y;
    #pragma unroll
    for (int off = 32; off; off >>= 1) {
        s  += __shfl_down(s,  off);
        ss += __shfl_down(ss, off);
    }
    __shared__ float ws0[4], ws1[4];
    int wid = t >> 6, lane = t & 63;
    if (lane == 0) { ws0[wid] = s; ws1[wid] = ss; }
    __syncthreads();
    __shared__ float mu_s, rstd_s;
    if (t == 0) {
        float S0 = ws0[0] + ws0[1] + ws0[2] + ws0[3];
        float S1 = ws1[0] + ws1[1] + ws1[2] + ws1[3];
        float mu = S0 * (1.0f / DD);
        float var = S1 * (1.0f / DD) - mu * mu;
        mu_s = mu;
        rstd_s = rsqrtf(var + EPS);
    }
    __syncthreads();
    float mu = mu_s, rstd = rstd_s;
    float2 g = ((const float2*)gamma)[t];
    float2 bb = ((const float2*)beta)[t];
    float2 o;
    o.x = (v.x - mu) * rstd * g.x + bb.x;
    o.y = (v.y - mu) * rstd * g.y + bb.y;
    ((float2*)(y + (size_t)row * DD))[t] = o;
}

// ---------------- prep: LN(seq_v) + cast q/k + cast W (fused) --------------
__global__ __launch_bounds__(256) void prep_kernel(const float* __restrict__ seq_v,
                                                   const float* __restrict__ seq_q,
                                                   const float* __restrict__ seq_k,
                                                   const float* __restrict__ W1,
                                                   const float* __restrict__ W2,
                                                   const float* __restrict__ W3,
                                                   const float* __restrict__ gamma,
                                                   const float* __restrict__ beta,
                                                   float* __restrict__ v_in,
                                                   _Float16* __restrict__ v16,
                                                   _Float16* __restrict__ qk16,
                                                   _Float16* __restrict__ w16) {
    int bid = blockIdx.x;
    int t = threadIdx.x;
    if (bid < NTOK) {
        int row = bid;
        float2 v = ((const float2*)(seq_v + (size_t)row * DD))[t];
        float s = v.x + v.y;
        float ss = v.x * v.x + v.y * v.y;
        #pragma unroll
        for (int off = 32; off; off >>= 1) {
            s  += __shfl_down(s,  off);
            ss += __shfl_down(ss, off);
        }
        __shared__ float ws0[4], ws1[4];
        int wid = t >> 6, lane = t & 63;
        if (lane == 0) { ws0[wid] = s; ws1[wid] = ss; }
        __syncthreads();
        __shared__ float mu_s, rstd_s;
        if (t == 0) {
            float S0 = ws0[0] + ws0[1] + ws0[2] + ws0[3];
            float S1 = ws1[0] + ws1[1] + ws1[2] + ws1[3];
            float mu = S0 * (1.0f / DD);
            float var = S1 * (1.0f / DD) - mu * mu;
            mu_s = mu;
            rstd_s = rsqrtf(var + EPS);
        }
        __syncthreads();
        float mu = mu_s, rstd = rstd_s;
        float2 g = ((const float2*)gamma)[t];
        float2 bb = ((const float2*)beta)[t];
        float2 o;
        o.x = (v.x - mu) * rstd * g.x + bb.x;
        o.y = (v.y - mu) * rstd * g.y + bb.y;
        ((float2*)(v_in + (size_t)row * DD))[t] = o;
        *(half2v*)&v16[(size_t)row * DD + 2 * t] = pack2(o.x, o.y);
    } else if (bid < 2 * NTOK) {
        size_t i = ((size_t)(bid - NTOK) * 256 + t) * 4;
        const float* src = (i < NE) ? (seq_q + i) : (seq_k + (i - NE));
        float4 v = *(const float4*)src;
        *(half4v*)(qk16 + i) = pack4(v.x, v.y, v.z, v.w);
    } else {
        size_t i = ((size_t)(bid - 2 * NTOK) * 256 + t) * 4;
        const float* src; float sc;
        if (i < WN)          { src = W1 + i;            sc = LOG2E; }
        else if (i < 2 * WN) { src = W2 + (i - WN);     sc = 1.0f; }
        else                 { src = W3 + (i - 2 * WN); sc = 1.0f; }
        float4 v = *(const float4*)src;
        *(half4v*)(w16 + i) = pack4(v.x * sc, v.y * sc, v.z * sc, v.w * sc);
    }
}

// ---------------- MFMA GEMM: all three projections in one launch ------------
// Round-4: double-buffered K-loop (attn's proven prefetch-after-barrier
// pattern; one barrier per K-step, loads for k+1 in flight during compute
// of k) + XCD-grouped 1D grid (each XCD owns 8 m-panels x 4 n-blocks per z,
// so the shared A-panel + W stay L2-resident per XCD).
#define GBM 128
#define GBN 128
#define GBK 64
__global__ __launch_bounds__(256) void gemm_mfma(const _Float16* __restrict__ Aall,
                                                 const _Float16* __restrict__ Wall,
                                                 _Float16* __restrict__ Call,
                                                 _Float16* __restrict__ vtOut) {
    __shared__ __align__(16) _Float16 smem[2][2 * GBM * GBK];   // 64KB: 2 x (A|W)
    // XCD-grouped decode of the flat 768-block grid. xcd = wg&7 (dispatch
    // round-robins XCDs); each XCD gets 8 consecutive m-panels x 4 n x 3 z.
    int wg = blockIdx.x;
    int local = wg >> 3;                 // 0..95
    int z = local >> 5;                  // 0..2
    int r5 = local & 31;
    int my = (wg & 7) * 8 + (r5 >> 2);   // 0..63  (m-panel)
    int nx = r5 & 3;                     // 0..3   (n-panel)
    bool isv = (z == 2);
    const _Float16* A = Aall + (size_t)z * NE;
    const _Float16* W = Wall + (size_t)z * WN;
    int t = threadIdx.x, w = t >> 6, lane = t & 63, q = lane >> 4, ln = lane & 15;
    int lrow = lane >> 3, lseg = lane & 7;
    int m0 = my * GBM, n0 = nx * GBN;
    int wm = w & 1, wn = w >> 1;
    f32x4 acc[4][4];
    #pragma unroll
    for (int mt = 0; mt < 4; ++mt)
        #pragma unroll
        for (int nt = 0; nt < 4; ++nt)
            acc[mt][nt] = (f32x4){0.f, 0.f, 0.f, 0.f};

    int gs = lseg ^ lrow;

    // stage K-tile k0 into buffer buf (async; drained by next barrier)
    auto stage = [&](int k0, int buf) {
        _Float16* Asb = smem[buf];
        _Float16* Wsb = smem[buf] + GBM * GBK;
        #pragma unroll
        for (int p = 0; p < 4; ++p) {
            int rr = w * 32 + p * 8 + lrow;
            gload_lds16(A + (size_t)(m0 + rr) * DD + k0 + gs * 8,
                        Asb + (size_t)(w * 32 + p * 8) * GBK);
            gload_lds16(W + (size_t)(n0 + rr) * DD + k0 + gs * 8,
                        Wsb + (size_t)(w * 32 + p * 8) * GBK);
        }
    };

    stage(0, 0);
    const int NK = DD / GBK;   // 8
    for (int ki = 0; ki < NK; ++ki) {
        int cur = ki & 1;
        __syncthreads();   // implicit vmcnt(0) drain: buffer `cur` resident
        if (ki + 1 < NK) stage((ki + 1) * GBK, cur ^ 1);   // prefetch in flight
        _Float16* Asb = smem[cur];
        _Float16* Wsb = smem[cur] + GBM * GBK;
        __builtin_amdgcn_s_setprio(1);
        #pragma unroll
        for (int kk = 0; kk < 2; ++kk) {
            int ch = ((4 * kk + q) ^ (ln & 7)) * 8;
            half8v af[4], wf[4];
            #pragma unroll
            for (int mt = 0; mt < 4; ++mt)
                af[mt] = *(half8v*)&Asb[(wm * 64 + mt * 16 + ln) * GBK + ch];
            #pragma unroll
            for (int nt = 0; nt < 4; ++nt)
                wf[nt] = *(half8v*)&Wsb[(wn * 64 + nt * 16 + ln) * GBK + ch];
            if (!isv) {
                #pragma unroll
                for (int mt = 0; mt < 4; ++mt)
                    #pragma unroll
                    for (int nt = 0; nt < 4; ++nt)
                        acc[mt][nt] = __builtin_amdgcn_mfma_f32_16x16x32_f16(
                            wf[nt], af[mt], acc[mt][nt], 0, 0, 0);  // C^T
            } else {
                #pragma unroll
                for (int mt = 0; mt < 4; ++mt)
                    #pragma unroll
                    for (int nt = 0; nt < 4; ++nt)
                        acc[mt][nt] = __builtin_amdgcn_mfma_f32_16x16x32_f16(
                            af[mt], wf[nt], acc[mt][nt], 0, 0, 0);  // C
            }
        }
        __builtin_amdgcn_s_setprio(0);
    }

    // ---- epilogue: stage 128x128 f16 tile in LDS (16B-chunk XOR swizzle),
    //      then fully-coalesced 16B stores. Last loop iter read smem[1];
    //      epilogue writes smem[0]'s 32KB — disjoint, no barrier needed
    //      before the writes; one barrier before the cross-thread read-back.
    _Float16* esm = &smem[0][0];
    if (!isv) {
        #pragma unroll
        for (int mt = 0; mt < 4; ++mt) {
            int mloc = wm * 64 + mt * 16 + ln;            // token-local row
            #pragma unroll
            for (int nt = 0; nt < 4; ++nt) {
                int nloc = wn * 64 + nt * 16 + q * 4;     // d-local col
                int cs = (nloc >> 3) ^ (mloc & 7);
                char* p = (char*)esm + mloc * 256 + cs * 16 + (nloc & 7) * 2;
                *(half4v*)p = pack4(acc[mt][nt][0], acc[mt][nt][1],
                                    acc[mt][nt][2], acc[mt][nt][3]);
            }
        }
    } else {
        #pragma unroll
        for (int nt = 0; nt < 4; ++nt) {
            int dloc = wn * 64 + nt * 16 + ln;            // d-local row
            #pragma unroll
            for (int mt = 0; mt < 4; ++mt) {
                int sloc = wm * 64 + mt * 16 + q * 4;     // token-local col
                int cs = (sloc >> 3) ^ (dloc & 7);
                char* p = (char*)esm + dloc * 256 + cs * 16 + (sloc & 7) * 2;
                *(half4v*)p = pack4(acc[mt][nt][0], acc[mt][nt][1],
                                    acc[mt][nt][2], acc[mt][nt][3]);
            }
        }
    }
    __syncthreads();
    int bq = m0 >> 11, sbase = m0 & (SS - 1);   // block never crosses a batch
    if (!isv) {
        _Float16* C = Call + (size_t)z * NE;
        #pragma unroll
        for (int p = 0; p < 8; ++p) {
            int id = p * 256 + t;                 // 0..2047
            int rr = id >> 4, c = id & 15;        // token row, d-chunk
            half8v vv = *(half8v*)((char*)esm + rr * 256 + ((c ^ (rr & 7)) * 16));
            int n = n0 + c * 8;
            int h = n >> 6, d0 = n & 63;
            *(half8v*)&C[((size_t)(bq * HH + h) * SS + (sbase + rr)) * HD + d0] = vv;
        }
    } else {
        #pragma unroll
        for (int p = 0; p < 8; ++p) {
            int id = p * 256 + t;
            int rr = id >> 4, c = id & 15;        // d row, token chunk
            half8v vv = *(half8v*)((char*)esm + rr * 256 + ((c ^ (rr & 7)) * 16));
            int d = n0 + rr;
            int h = d >> 6, dd = d & 63;
            *(half8v*)&vtOut[((size_t)(bq * HH + h) * HD + dd) * SS + sbase + c * 8] = vv;
        }
    }
}

// ---------------- Flash attention, S^T orientation, double-buffered --------
// Round-0 body (known-good 62us): 512 threads = 8 waves, 16 i-rows per wave.
// Per rounds 1-2: the kernel is SIMD-issue-bound (VALU 41% + MFMA 24%);
// occupancy and S-pipelining are not levers. Kept: XCD swizzle (FETCH 5.7x
// lower), setprio around MFMA clusters, defer-max threshold.
#define AI 128
#define AJ 64
__global__ __launch_bounds__(512, 4) void attn_mfma(const _Float16* __restrict__ qh,
                                                    const _Float16* __restrict__ kh,
                                                    const _Float16* __restrict__ vt,
                                                    float* __restrict__ out) {
    __shared__ __align__(16) _Float16 Qt[2][AJ * HD];   // 64 j x 64 d (swizzled)
    __shared__ __align__(16) _Float16 Vs[2][HD * AJ];   // 64 d x 64 j (swizzled)
    __shared__ __align__(16) _Float16 Ps[AI * AJ];      // wave-private P rows
    int t = threadIdx.x, w = t >> 6, lane = t & 63, q = lane >> 4, ln = lane & 15;
    // XCD-aware swizzle: xcd = wg&7 (round-robin dispatch); each XCD owns 4
    // whole (b,h) so their Q+V streams stay L2-resident across 16 i-blocks.
    int wg = blockIdx.x;
    int slot = wg >> 3;
    int bh = (wg & 7) * 4 + (slot >> 4);
    int i0 = (slot & 15) * AI;
    int b = bh >> 3, h = bh & 7;
    const _Float16* Kb = kh + (size_t)bh * SS * HD;
    const _Float16* Qb = qh + (size_t)bh * SS * HD;
    const _Float16* Vb = vt + (size_t)bh * HD * SS;

    // K fragments (B-operand): row i = i0 + w*16 + ln, in regs for all j
    half8v kf[2];
    #pragma unroll
    for (int kk = 0; kk < 2; ++kk)
        kf[kk] = *(const half8v*)&Kb[(size_t)(i0 + w * 16 + ln) * HD + kk * 32 + q * 8];

    f32x4 oacc[4], lacc;
    float m_run = -3.0e38f;
    lacc = (f32x4){0.f, 0.f, 0.f, 0.f};
    #pragma unroll
    for (int mtd = 0; mtd < 4; ++mtd) oacc[mtd] = (f32x4){0.f, 0.f, 0.f, 0.f};
    half8v ones;
    #pragma unroll
    for (int e = 0; e < 8; ++e) ones[e] = (_Float16)1.0f;
    const f32x4 zf = (f32x4){0.f, 0.f, 0.f, 0.f};

    // staging: each thread stages one 16B chunk of Qt and one of Vs
    int sr = t >> 3;          // 0..63 (row)
    int sc = t & 7;           // chunk slot
    int ssw = sc ^ (sr & 7);  // swizzled source chunk

    // prologue: stage tile 0 into buffer 0
    gload_lds16(Qb + (size_t)sr * HD + ssw * 8, &Qt[0][(size_t)w * 512]);
    gload_lds16(Vb + (size_t)sr * SS + ssw * 8, &Vs[0][(size_t)w * 512]);

    const int NITER = SS / AJ;
    for (int jt = 0; jt < NITER; ++jt) {
        int cur = jt & 1;
        __syncthreads();   // drains vmcnt -> buffer `cur` ready; prior reads done

        // prefetch next tile into the other buffer (in flight during compute)
        if (jt + 1 < NITER) {
            int j1 = (jt + 1) * AJ;
            gload_lds16(Qb + (size_t)(j1 + sr) * HD + ssw * 8, &Qt[cur ^ 1][(size_t)w * 512]);
            gload_lds16(Vb + (size_t)sr * SS + j1 + ssw * 8,   &Vs[cur ^ 1][(size_t)w * 512]);
        }

        // ---- S^T = Q.K^T : M=j(64), N=i(16/wave), K=d(64) ----
        f32x4 sacc[4];
        __builtin_amdgcn_s_setprio(1);
        #pragma unroll
        for (int mt = 0; mt < 4; ++mt) {
            half8v qf = *(half8v*)&Qt[cur][(mt * 16 + ln) * HD + (q ^ (ln & 7)) * 8];
            sacc[mt] = __builtin_amdgcn_mfma_f32_16x16x32_f16(qf, kf[0], zf, 0, 0, 0);
        }
        #pragma unroll
        for (int mt = 0; mt < 4; ++mt) {
            half8v qf = *(half8v*)&Qt[cur][(mt * 16 + ln) * HD + ((4 + q) ^ (ln & 7)) * 8];
            sacc[mt] = __builtin_amdgcn_mfma_f32_16x16x32_f16(qf, kf[1], sacc[mt], 0, 0, 0);
        }
        __builtin_amdgcn_s_setprio(0);

        // ---- online softmax over j (16 local + 2 shuffles) ----
        float mx = fmaxf(fmaxf(sacc[0][0], sacc[0][1]), fmaxf(sacc[0][2], sacc[0][3]));
        #pragma unroll
        for (int mt = 1; mt < 4; ++mt) {
            float m2 = fmaxf(fmaxf(sacc[mt][0], sacc[mt][1]),
                             fmaxf(sacc[mt][2], sacc[mt][3]));
            mx = fmaxf(mx, m2);
        }
        mx = fmaxf(mx, __shfl_xor(mx, 16));
        mx = fmaxf(mx, __shfl_xor(mx, 32));
        // defer-max (T13): rescale only when max grew by >7 (log2 domain;
        // W1 pre-scaled by log2e). P bounded by 2^7, fits f16; the common
        // scale cancels in the epilogue divide.
        if (__any(mx > m_run + 7.0f)) {
            float mn = fmaxf(m_run, mx);
            float a = fast_exp2(m_run - mn);
            lacc *= a;
            #pragma unroll
            for (int mtd = 0; mtd < 4; ++mtd) oacc[mtd] *= a;
            m_run = mn;
        }

        // ---- P = exp2(S^T - m) -> wave-private LDS rows (no barrier) ----
        int rp = w * 16 + ln;
        #pragma unroll
        for (int mt = 0; mt < 4; ++mt) {
            float p0 = fast_exp2(sacc[mt][0] - m_run);
            float p1 = fast_exp2(sacc[mt][1] - m_run);
            float p2 = fast_exp2(sacc[mt][2] - m_run);
            float p3 = fast_exp2(sacc[mt][3] - m_run);
            int cw = mt * 2 + (q >> 1);
            int pos = cw ^ (ln & 7);
            *(half4v*)&Ps[(size_t)rp * AJ + pos * 8 + (q & 1) * 4] =
                pack4(p0, p1, p2, p3);
        }

        // ---- O^T += V^T.P^T ; l += 1.P^T  (M=d, N=i, K=j) ----
        __builtin_amdgcn_s_setprio(1);
        #pragma unroll
        for (int ks = 0; ks < 2; ++ks) {
            int pos = ((ks * 4 + q) ^ (ln & 7)) * 8;
            half8v pf = *(half8v*)&Ps[(size_t)(w * 16 + ln) * AJ + pos];
            lacc = __builtin_amdgcn_mfma_f32_16x16x32_f16(ones, pf, lacc, 0, 0, 0);
            #pragma unroll
            for (int mtd = 0; mtd < 4; ++mtd) {
                half8v vf = *(half8v*)&Vs[cur][(size_t)(mtd * 16 + ln) * AJ + pos];
                oacc[mtd] = __builtin_amdgcn_mfma_f32_16x16x32_f16(vf, pf, oacc[mtd], 0, 0, 0);
            }
        }
        __builtin_amdgcn_s_setprio(0);
    }

    // ---- epilogue: O[i][d] = O^T[d][i] / l ----
    float inv = 1.0f / lacc[0];
    int i = i0 + w * 16 + ln;
    #pragma unroll
    for (int mtd = 0; mtd < 4; ++mtd) {
        float4 o;
        o.x = oacc[mtd][0] * inv;
        o.y = oacc[mtd][1] * inv;
        o.z = oacc[mtd][2] * inv;
        o.w = oacc[mtd][3] * inv;
        *(float4*)&out[(size_t)(b * SS + i) * DD + h * HD + mtd * 16 + q * 4] = o;
    }
}

extern "C" void kernel_launch(void* const* d_in, const int* in_sizes, int n_in,
                              void* d_out, int out_size, void* d_ws, size_t ws_size,
                              hipStream_t stream) {
    const float* seq_k = (const float*)d_in[0];
    const float* seq_q = (const float*)d_in[1];
    const float* seq_v = (const float*)d_in[2];
    const float* W1    = (const float*)d_in[3];
    const float* W2    = (const float*)d_in[4];
    const float* W3    = (const float*)d_in[5];
    const float* gamma = (const float*)d_in[6];
    const float* beta  = (const float*)d_in[7];
    float* out = (float*)d_out;

    const size_t MB = 1024 * 1024;
    char* w8 = (char*)d_ws;
    float*    v_in = (float*)w8;                    // [0,16) MB fp32 residual
    _Float16* a16  = (_Float16*)(w8 + 16 * MB);     // q16,k16,v16 [16,40)
    _Float16* w16  = (_Float16*)(w8 + 40 * MB);     // [40,42)
    _Float16* qh   = (_Float16*)(w8 + 48 * MB);     // [48,56)
    _Float16* vt   = (_Float16*)(w8 + 64 * MB);     // [64,72)
    float*    ao   = (float*)(w8 + 16 * MB);        // aliases a16/w16 (dead post-gemm)

    _Float16* q16 = a16;                // q,k contiguous for fused cast
    _Float16* v16 = a16 + 2 * NE;
    _Float16* kh  = qh + NE;

    // 1. fused prep: LN(seq_v) + cast q/k + cast W (W1 pre-scaled by log2e)
    hipLaunchKernelGGL(prep_kernel, dim3(2 * NTOK + 768), dim3(256), 0, stream,
                       seq_v, seq_q, seq_k, W1, W2, W3, gamma, beta,
                       v_in, v16, q16, w16);
    // 2. projections (double-buffered, XCD-grouped 1D grid)
    hipLaunchKernelGGL(gemm_mfma, dim3((DD / GBN) * (NTOK / GBM) * 3), dim3(256), 0, stream,
                       a16, w16, qh, vt);
    // 3. flash attention (double-buffered, XCD-swizzled)
    hipLaunchKernelGGL(attn_mfma, dim3((SS / AI) * BB * HH), dim3(512), 0, stream,
                       qh, kh, vt, ao);
    // 4. residual + final LN
    hipLaunchKernelGGL(ln_kernel, dim3(NTOK), dim3(256), 0, stream,
                       ao, v_in, gamma, beta, out);
}

// Round 5
// 180.667 us; speedup vs baseline: 1.1266x; 1.0195x over previous
//
#include <hip/hip_runtime.h>
#include <math.h>

#define BB 4
#define SS 2048
#define DD 512
#define HH 8
#define HD 64
#define NTOK (BB*SS)
#define EPS 1e-5f
#define NE ((size_t)NTOK * DD)
#define WN ((size_t)DD * DD)
#define LOG2E 1.4426950408889634f

typedef _Float16 half8v __attribute__((ext_vector_type(8)));
typedef _Float16 half4v __attribute__((ext_vector_type(4)));
typedef _Float16 half2v __attribute__((ext_vector_type(2)));
typedef float f32x4 __attribute__((ext_vector_type(4)));

__device__ __forceinline__ float fast_exp2(float x) {
#if __has_builtin(__builtin_amdgcn_exp2f)
    return __builtin_amdgcn_exp2f(x);
#else
    return __expf(x * 0.6931471805599453f);
#endif
}

__device__ __forceinline__ half2v pack2(float a, float b) {
    return __builtin_bit_cast(half2v, __builtin_amdgcn_cvt_pkrtz(a, b));
}

__device__ __forceinline__ half4v pack4(float a, float b, float c, float d) {
    half2v lo = pack2(a, b);
    half2v hi = pack2(c, d);
    half4v r; r[0] = lo[0]; r[1] = lo[1]; r[2] = hi[0]; r[3] = hi[1];
    return r;
}

__device__ __forceinline__ void gload_lds16(const void* g, void* l) {
    __builtin_amdgcn_global_load_lds(
        (const __attribute__((address_space(1))) unsigned int*)g,
        (__attribute__((address_space(3))) unsigned int*)l, 16, 0, 0);
}

// ---------------- final LayerNorm (residual from f16 v16, x from f16 ao) ---
__global__ __launch_bounds__(256) void ln_kernel(const _Float16* __restrict__ x,
                                                 const _Float16* __restrict__ res,
                                                 const float* __restrict__ gamma,
                                                 const float* __restrict__ beta,
                                                 float* __restrict__ y) {
    int row = blockIdx.x;
    int t = threadIdx.x;
    half2v xv = *(const half2v*)&x[(size_t)row * DD + 2 * t];
    half2v rv = *(const half2v*)&res[(size_t)row * DD + 2 * t];
    float2 v;
    v.x = (float)xv[0] + (float)rv[0];
    v.y = (float)xv[1] + (float)rv[1];
    float s = v.x + v.y;
    float ss = v.x * v.x + v.y * v.y;
    #pragma unroll
    for (int off = 32; off; off >>= 1) {
        s  += __shfl_down(s,  off);
        ss += __shfl_down(ss, off);
    }
    __shared__ float ws0[4], ws1[4];
    int wid = t >> 6, lane = t & 63;
    if (lane == 0) { ws0[wid] = s; ws1[wid] = ss; }
    __syncthreads();
    __shared__ float mu_s, rstd_s;
    if (t == 0) {
        float S0 = ws0[0] + ws0[1] + ws0[2] + ws0[3];
        float S1 = ws1[0] + ws1[1] + ws1[2] + ws1[3];
        float mu = S0 * (1.0f / DD);
        float var = S1 * (1.0f / DD) - mu * mu;
        mu_s = mu;
        rstd_s = rsqrtf(var + EPS);
    }
    __syncthreads();
    float mu = mu_s, rstd = rstd_s;
    float2 g = ((const float2*)gamma)[t];
    float2 bb = ((const float2*)beta)[t];
    float2 o;
    o.x = (v.x - mu) * rstd * g.x + bb.x;
    o.y = (v.y - mu) * rstd * g.y + bb.y;
    ((float2*)(y + (size_t)row * DD))[t] = o;
}

// ---------------- prep: LN(seq_v) -> f16 only + cast q/k + cast W ----------
__global__ __launch_bounds__(256) void prep_kernel(const float* __restrict__ seq_v,
                                                   const float* __restrict__ seq_q,
                                                   const float* __restrict__ seq_k,
                                                   const float* __restrict__ W1,
                                                   const float* __restrict__ W2,
                                                   const float* __restrict__ W3,
                                                   const float* __restrict__ gamma,
                                                   const float* __restrict__ beta,
                                                   _Float16* __restrict__ v16,
                                                   _Float16* __restrict__ qk16,
                                                   _Float16* __restrict__ w16) {
    int bid = blockIdx.x;
    int t = threadIdx.x;
    if (bid < NTOK) {
        int row = bid;
        float2 v = ((const float2*)(seq_v + (size_t)row * DD))[t];
        float s = v.x + v.y;
        float ss = v.x * v.x + v.y * v.y;
        #pragma unroll
        for (int off = 32; off; off >>= 1) {
            s  += __shfl_down(s,  off);
            ss += __shfl_down(ss, off);
        }
        __shared__ float ws0[4], ws1[4];
        int wid = t >> 6, lane = t & 63;
        if (lane == 0) { ws0[wid] = s; ws1[wid] = ss; }
        __syncthreads();
        __shared__ float mu_s, rstd_s;
        if (t == 0) {
            float S0 = ws0[0] + ws0[1] + ws0[2] + ws0[3];
            float S1 = ws1[0] + ws1[1] + ws1[2] + ws1[3];
            float mu = S0 * (1.0f / DD);
            float var = S1 * (1.0f / DD) - mu * mu;
            mu_s = mu;
            rstd_s = rsqrtf(var + EPS);
        }
        __syncthreads();
        float mu = mu_s, rstd = rstd_s;
        float2 g = ((const float2*)gamma)[t];
        float2 bb = ((const float2*)beta)[t];
        float2 o;
        o.x = (v.x - mu) * rstd * g.x + bb.x;
        o.y = (v.y - mu) * rstd * g.y + bb.y;
        *(half2v*)&v16[(size_t)row * DD + 2 * t] = pack2(o.x, o.y);
    } else if (bid < 2 * NTOK) {
        size_t i = ((size_t)(bid - NTOK) * 256 + t) * 4;
        const float* src = (i < NE) ? (seq_q + i) : (seq_k + (i - NE));
        float4 v = *(const float4*)src;
        *(half4v*)(qk16 + i) = pack4(v.x, v.y, v.z, v.w);
    } else {
        size_t i = ((size_t)(bid - 2 * NTOK) * 256 + t) * 4;
        const float* src; float sc;
        if (i < WN)          { src = W1 + i;            sc = LOG2E; }
        else if (i < 2 * WN) { src = W2 + (i - WN);     sc = 1.0f; }
        else                 { src = W3 + (i - 2 * WN); sc = 1.0f; }
        float4 v = *(const float4*)src;
        *(half4v*)(w16 + i) = pack4(v.x * sc, v.y * sc, v.z * sc, v.w * sc);
    }
}

// ---------------- MFMA GEMM: all three projections in one launch ------------
// Double-buffered K-loop (prefetch-after-barrier) + XCD-grouped 1D grid.
#define GBM 128
#define GBN 128
#define GBK 64
__global__ __launch_bounds__(256) void gemm_mfma(const _Float16* __restrict__ Aall,
                                                 const _Float16* __restrict__ Wall,
                                                 _Float16* __restrict__ Call,
                                                 _Float16* __restrict__ vtOut) {
    __shared__ __align__(16) _Float16 smem[2][2 * GBM * GBK];   // 64KB: 2 x (A|W)
    int wg = blockIdx.x;
    int local = wg >> 3;                 // 0..95
    int z = local >> 5;                  // 0..2
    int r5 = local & 31;
    int my = (wg & 7) * 8 + (r5 >> 2);   // 0..63  (m-panel)
    int nx = r5 & 3;                     // 0..3   (n-panel)
    bool isv = (z == 2);
    const _Float16* A = Aall + (size_t)z * NE;
    const _Float16* W = Wall + (size_t)z * WN;
    int t = threadIdx.x, w = t >> 6, lane = t & 63, q = lane >> 4, ln = lane & 15;
    int lrow = lane >> 3, lseg = lane & 7;
    int m0 = my * GBM, n0 = nx * GBN;
    int wm = w & 1, wn = w >> 1;
    f32x4 acc[4][4];
    #pragma unroll
    for (int mt = 0; mt < 4; ++mt)
        #pragma unroll
        for (int nt = 0; nt < 4; ++nt)
            acc[mt][nt] = (f32x4){0.f, 0.f, 0.f, 0.f};

    int gs = lseg ^ lrow;

    auto stage = [&](int k0, int buf) {
        _Float16* Asb = smem[buf];
        _Float16* Wsb = smem[buf] + GBM * GBK;
        #pragma unroll
        for (int p = 0; p < 4; ++p) {
            int rr = w * 32 + p * 8 + lrow;
            gload_lds16(A + (size_t)(m0 + rr) * DD + k0 + gs * 8,
                        Asb + (size_t)(w * 32 + p * 8) * GBK);
            gload_lds16(W + (size_t)(n0 + rr) * DD + k0 + gs * 8,
                        Wsb + (size_t)(w * 32 + p * 8) * GBK);
        }
    };

    stage(0, 0);
    const int NK = DD / GBK;   // 8
    for (int ki = 0; ki < NK; ++ki) {
        int cur = ki & 1;
        __syncthreads();
        if (ki + 1 < NK) stage((ki + 1) * GBK, cur ^ 1);
        _Float16* Asb = smem[cur];
        _Float16* Wsb = smem[cur] + GBM * GBK;
        __builtin_amdgcn_s_setprio(1);
        #pragma unroll
        for (int kk = 0; kk < 2; ++kk) {
            int ch = ((4 * kk + q) ^ (ln & 7)) * 8;
            half8v af[4], wf[4];
            #pragma unroll
            for (int mt = 0; mt < 4; ++mt)
                af[mt] = *(half8v*)&Asb[(wm * 64 + mt * 16 + ln) * GBK + ch];
            #pragma unroll
            for (int nt = 0; nt < 4; ++nt)
                wf[nt] = *(half8v*)&Wsb[(wn * 64 + nt * 16 + ln) * GBK + ch];
            if (!isv) {
                #pragma unroll
                for (int mt = 0; mt < 4; ++mt)
                    #pragma unroll
                    for (int nt = 0; nt < 4; ++nt)
                        acc[mt][nt] = __builtin_amdgcn_mfma_f32_16x16x32_f16(
                            wf[nt], af[mt], acc[mt][nt], 0, 0, 0);  // C^T
            } else {
                #pragma unroll
                for (int mt = 0; mt < 4; ++mt)
                    #pragma unroll
                    for (int nt = 0; nt < 4; ++nt)
                        acc[mt][nt] = __builtin_amdgcn_mfma_f32_16x16x32_f16(
                            af[mt], wf[nt], acc[mt][nt], 0, 0, 0);  // C
            }
        }
        __builtin_amdgcn_s_setprio(0);
    }

    // ---- epilogue: swizzled 128x128 f16 LDS tile -> coalesced 16B stores
    _Float16* esm = &smem[0][0];
    if (!isv) {
        #pragma unroll
        for (int mt = 0; mt < 4; ++mt) {
            int mloc = wm * 64 + mt * 16 + ln;
            #pragma unroll
            for (int nt = 0; nt < 4; ++nt) {
                int nloc = wn * 64 + nt * 16 + q * 4;
                int cs = (nloc >> 3) ^ (mloc & 7);
                char* p = (char*)esm + mloc * 256 + cs * 16 + (nloc & 7) * 2;
                *(half4v*)p = pack4(acc[mt][nt][0], acc[mt][nt][1],
                                    acc[mt][nt][2], acc[mt][nt][3]);
            }
        }
    } else {
        #pragma unroll
        for (int nt = 0; nt < 4; ++nt) {
            int dloc = wn * 64 + nt * 16 + ln;
            #pragma unroll
            for (int mt = 0; mt < 4; ++mt) {
                int sloc = wm * 64 + mt * 16 + q * 4;
                int cs = (sloc >> 3) ^ (dloc & 7);
                char* p = (char*)esm + dloc * 256 + cs * 16 + (sloc & 7) * 2;
                *(half4v*)p = pack4(acc[mt][nt][0], acc[mt][nt][1],
                                    acc[mt][nt][2], acc[mt][nt][3]);
            }
        }
    }
    __syncthreads();
    int bq = m0 >> 11, sbase = m0 & (SS - 1);
    if (!isv) {
        _Float16* C = Call + (size_t)z * NE;
        #pragma unroll
        for (int p = 0; p < 8; ++p) {
            int id = p * 256 + t;
            int rr = id >> 4, c = id & 15;
            half8v vv = *(half8v*)((char*)esm + rr * 256 + ((c ^ (rr & 7)) * 16));
            int n = n0 + c * 8;
            int h = n >> 6, d0 = n & 63;
            *(half8v*)&C[((size_t)(bq * HH + h) * SS + (sbase + rr)) * HD + d0] = vv;
        }
    } else {
        #pragma unroll
        for (int p = 0; p < 8; ++p) {
            int id = p * 256 + t;
            int rr = id >> 4, c = id & 15;
            half8v vv = *(half8v*)((char*)esm + rr * 256 + ((c ^ (rr & 7)) * 16));
            int d = n0 + rr;
            int h = d >> 6, dd = d & 63;
            *(half8v*)&vtOut[((size_t)(bq * HH + h) * HD + dd) * SS + sbase + c * 8] = vv;
        }
    }
}

// ---------------- Flash attention, S^T orientation, double-buffered --------
// Round-5: j-loop unrolled x2 so the buffer index is COMPILE-TIME. With a
// runtime `cur`, every LDS address was a fresh select+xor+add chain each
// iter (VGPR_Count=40 showed nothing was hoisted; VALUBusy 42% was mostly
// addressing). Compile-time bases let LICM keep all swizzled offsets in
// registers. Output ao is now f16 (halves the write traffic).
#define AI 128
#define AJ 64
__global__ __launch_bounds__(512, 4) void attn_mfma(const _Float16* __restrict__ qh,
                                                    const _Float16* __restrict__ kh,
                                                    const _Float16* __restrict__ vt,
                                                    _Float16* __restrict__ outp) {
    __shared__ __align__(16) _Float16 Qt[2][AJ * HD];   // 64 j x 64 d (swizzled)
    __shared__ __align__(16) _Float16 Vs[2][HD * AJ];   // 64 d x 64 j (swizzled)
    __shared__ __align__(16) _Float16 Ps[AI * AJ];      // wave-private P rows
    int t = threadIdx.x, w = t >> 6, lane = t & 63, q = lane >> 4, ln = lane & 15;
    // XCD-aware swizzle: each XCD owns 4 whole (b,h); Q+V streams L2-resident.
    int wg = blockIdx.x;
    int slot = wg >> 3;
    int bh = (wg & 7) * 4 + (slot >> 4);
    int i0 = (slot & 15) * AI;
    int b = bh >> 3, h = bh & 7;
    const _Float16* Kb = kh + (size_t)bh * SS * HD;
    const _Float16* Qb = qh + (size_t)bh * SS * HD;
    const _Float16* Vb = vt + (size_t)bh * HD * SS;

    half8v kf[2];
    #pragma unroll
    for (int kk = 0; kk < 2; ++kk)
        kf[kk] = *(const half8v*)&Kb[(size_t)(i0 + w * 16 + ln) * HD + kk * 32 + q * 8];

    f32x4 oacc[4], lacc;
    float m_run = -3.0e38f;
    lacc = (f32x4){0.f, 0.f, 0.f, 0.f};
    #pragma unroll
    for (int mtd = 0; mtd < 4; ++mtd) oacc[mtd] = (f32x4){0.f, 0.f, 0.f, 0.f};
    half8v ones;
    #pragma unroll
    for (int e = 0; e < 8; ++e) ones[e] = (_Float16)1.0f;
    const f32x4 zf = (f32x4){0.f, 0.f, 0.f, 0.f};

    int sr = t >> 3;          // 0..63 (row)
    int sc = t & 7;           // chunk slot
    int ssw = sc ^ (sr & 7);  // swizzled source chunk

    // prologue: stage tile 0 into buffer 0
    gload_lds16(Qb + (size_t)sr * HD + ssw * 8, &Qt[0][(size_t)w * 512]);
    gload_lds16(Vb + (size_t)sr * SS + ssw * 8, &Vs[0][(size_t)w * 512]);

    const int NITER = SS / AJ;   // 32 (even)

#define ATTN_STEP(JT, CUR, DOPF)                                              \
    {                                                                         \
        __syncthreads();                                                      \
        if (DOPF) {                                                           \
            int j1 = ((JT) + 1) * AJ;                                         \
            gload_lds16(Qb + (size_t)(j1 + sr) * HD + ssw * 8,                \
                        &Qt[(CUR) ^ 1][(size_t)w * 512]);                     \
            gload_lds16(Vb + (size_t)sr * SS + j1 + ssw * 8,                  \
                        &Vs[(CUR) ^ 1][(size_t)w * 512]);                     \
        }                                                                     \
        f32x4 sacc[4];                                                        \
        __builtin_amdgcn_s_setprio(1);                                        \
        _Pragma("unroll")                                                     \
        for (int mt = 0; mt < 4; ++mt) {                                      \
            half8v qf = *(half8v*)&Qt[CUR][(mt * 16 + ln) * HD +              \
                                           (q ^ (ln & 7)) * 8];               \
            sacc[mt] = __builtin_amdgcn_mfma_f32_16x16x32_f16(                \
                qf, kf[0], zf, 0, 0, 0);                                      \
        }                                                                     \
        _Pragma("unroll")                                                     \
        for (int mt = 0; mt < 4; ++mt) {                                      \
            half8v qf = *(half8v*)&Qt[CUR][(mt * 16 + ln) * HD +              \
                                           ((4 + q) ^ (ln & 7)) * 8];         \
            sacc[mt] = __builtin_amdgcn_mfma_f32_16x16x32_f16(                \
                qf, kf[1], sacc[mt], 0, 0, 0);                                \
        }                                                                     \
        __builtin_amdgcn_s_setprio(0);                                        \
        float mx = fmaxf(fmaxf(sacc[0][0], sacc[0][1]),                       \
                         fmaxf(sacc[0][2], sacc[0][3]));                      \
        _Pragma("unroll")                                                     \
        for (int mt = 1; mt < 4; ++mt) {                                      \
            float m2 = fmaxf(fmaxf(sacc[mt][0], sacc[mt][1]),                 \
                             fmaxf(sacc[mt][2], sacc[mt][3]));                \
            mx = fmaxf(mx, m2);                                               \
        }                                                                     \
        mx = fmaxf(mx, __shfl_xor(mx, 16));                                   \
        mx = fmaxf(mx, __shfl_xor(mx, 32));                                   \
        if (__any(mx > m_run + 7.0f)) {                                       \
            float mn = fmaxf(m_run, mx);                                      \
            float a = fast_exp2(m_run - mn);                                  \
            lacc *= a;                                                        \
            _Pragma("unroll")                                                 \
            for (int mtd = 0; mtd < 4; ++mtd) oacc[mtd] *= a;                 \
            m_run = mn;                                                       \
        }                                                                     \
        int rp = w * 16 + ln;                                                 \
        _Pragma("unroll")                                                     \
        for (int mt = 0; mt < 4; ++mt) {                                      \
            float p0 = fast_exp2(sacc[mt][0] - m_run);                        \
            float p1 = fast_exp2(sacc[mt][1] - m_run);                        \
            float p2 = fast_exp2(sacc[mt][2] - m_run);                        \
            float p3 = fast_exp2(sacc[mt][3] - m_run);                        \
            int cw = mt * 2 + (q >> 1);                                       \
            int pos = cw ^ (ln & 7);                                          \
            *(half4v*)&Ps[(size_t)rp * AJ + pos * 8 + (q & 1) * 4] =          \
                pack4(p0, p1, p2, p3);                                        \
        }                                                                     \
        __builtin_amdgcn_s_setprio(1);                                        \
        _Pragma("unroll")                                                     \
        for (int ks = 0; ks < 2; ++ks) {                                      \
            int pos = ((ks * 4 + q) ^ (ln & 7)) * 8;                          \
            half8v pf = *(half8v*)&Ps[(size_t)(w * 16 + ln) * AJ + pos];      \
            lacc = __builtin_amdgcn_mfma_f32_16x16x32_f16(                    \
                ones, pf, lacc, 0, 0, 0);                                     \
            _Pragma("unroll")                                                 \
            for (int mtd = 0; mtd < 4; ++mtd) {                               \
                half8v vf = *(half8v*)&Vs[CUR][(size_t)(mtd * 16 + ln) * AJ + \
                                               pos];                          \
                oacc[mtd] = __builtin_amdgcn_mfma_f32_16x16x32_f16(           \
                    vf, pf, oacc[mtd], 0, 0, 0);                              \
            }                                                                 \
        }                                                                     \
        __builtin_amdgcn_s_setprio(0);                                        \
    }

    for (int jtp = 0; jtp < NITER / 2; ++jtp) {
        int jt0 = 2 * jtp;
        ATTN_STEP(jt0, 0, true);
        ATTN_STEP(jt0 + 1, 1, (jtp + 1 < NITER / 2));
    }
#undef ATTN_STEP

    // ---- epilogue: O[i][d] = O^T[d][i] / l  (f16 output) ----
    float inv = 1.0f / lacc[0];
    int i = i0 + w * 16 + ln;
    #pragma unroll
    for (int mtd = 0; mtd < 4; ++mtd) {
        half4v o = pack4(oacc[mtd][0] * inv, oacc[mtd][1] * inv,
                         oacc[mtd][2] * inv, oacc[mtd][3] * inv);
        *(half4v*)&outp[(size_t)(b * SS + i) * DD + h * HD + mtd * 16 + q * 4] = o;
    }
}

extern "C" void kernel_launch(void* const* d_in, const int* in_sizes, int n_in,
                              void* d_out, int out_size, void* d_ws, size_t ws_size,
                              hipStream_t stream) {
    const float* seq_k = (const float*)d_in[0];
    const float* seq_q = (const float*)d_in[1];
    const float* seq_v = (const float*)d_in[2];
    const float* W1    = (const float*)d_in[3];
    const float* W2    = (const float*)d_in[4];
    const float* W3    = (const float*)d_in[5];
    const float* gamma = (const float*)d_in[6];
    const float* beta  = (const float*)d_in[7];
    float* out = (float*)d_out;

    const size_t MB = 1024 * 1024;
    char* w8 = (char*)d_ws;
    _Float16* ao   = (_Float16*)w8;                 // [0,8)  f16 attn out
    _Float16* a16  = (_Float16*)(w8 + 16 * MB);     // q16,k16,v16 [16,40)
    _Float16* w16  = (_Float16*)(w8 + 40 * MB);     // [40,42)
    _Float16* qh   = (_Float16*)(w8 + 48 * MB);     // [48,56)
    _Float16* vt   = (_Float16*)(w8 + 64 * MB);     // [64,72)

    _Float16* q16 = a16;                // q,k contiguous for fused cast
    _Float16* v16 = a16 + 2 * NE;       // [32,40) — residual, live until ln
    _Float16* kh  = qh + NE;

    // 1. fused prep: LN(seq_v)->f16 + cast q/k + cast W (W1 pre-scaled log2e)
    hipLaunchKernelGGL(prep_kernel, dim3(2 * NTOK + 768), dim3(256), 0, stream,
                       seq_v, seq_q, seq_k, W1, W2, W3, gamma, beta,
                       v16, q16, w16);
    // 2. projections (double-buffered, XCD-grouped 1D grid)
    hipLaunchKernelGGL(gemm_mfma, dim3((DD / GBN) * (NTOK / GBM) * 3), dim3(256), 0, stream,
                       a16, w16, qh, vt);
    // 3. flash attention (double-buffered, XCD-swizzled, unrolled x2)
    hipLaunchKernelGGL(attn_mfma, dim3((SS / AI) * BB * HH), dim3(512), 0, stream,
                       qh, kh, vt, ao);
    // 4. residual + final LN (f16 inputs)
    hipLaunchKernelGGL(ln_kernel, dim3(NTOK), dim3(256), 0, stream,
                       ao, v16, gamma, beta, out);
}